// Round 9
// baseline (475.652 us; speedup 1.0000x reference)
//
#include <hip/hip_runtime.h>

// LSTM B=256, T=1024, I=64, H=128. One block/batch row (256 blocks = 256 CUs).
// R17: 4-wave/32-col restructure of the VERIFIED f16 R10 kernel (sync A/B).
//  - Evidence: R10(16 f16 MFMA/wave/step)=977cyc/step, R16(8 i8)=~1040 --
//    step time invariant to MFMA work; MfmaUtil 24-50%, VALUBusy 40-44%,
//    no pipe saturated => step is serial-latency + cross-wave-sync bound.
//  - Change: 4 waves x 32 cols (2 col-tiles/wave) instead of 8 x 16.
//    Identical per-SIMD MFMA issue (1x32 vs 2x16), identical math/numerics.
//    Halves barrier width (4 waves), halves post-barrier LDS read burst
//    (8 vs 16 ds_read_b128), removes 2-wave/SIMD lockstep contention on the
//    VALU/trans unit during the activation chain.
//  - waves_per_eu(1,1): 1 wave/SIMD anyway -> 512-reg budget; demand ~180
//    arch + 192 AGPR (bfh 128 + bfx 64 as MFMA B-operands) -- no spill.
//  - Numerics byte-identical to R10 per column: exp2-folded weights, same
//    gate order (f,g first; i; o trailing), same c-rotation lineage.

typedef _Float16 half8  __attribute__((ext_vector_type(8)));
typedef _Float16 half2t __attribute__((ext_vector_type(2)));
typedef float  floatx4  __attribute__((ext_vector_type(4)));

constexpr int Tt = 1024;
constexpr int Ii = 64;
constexpr int Hh = 128;
constexpr int CH = 16;          // timesteps per x chunk-GEMM
constexpr int NCH = Tt / CH;    // 64 chunks

__device__ __forceinline__ float fast_rcp(float x) { return __builtin_amdgcn_rcpf(x); }
__device__ __forceinline__ float exp2_(float x)    { return __builtin_amdgcn_exp2f(x); }
__device__ __forceinline__ half2t pk16(float a, float b) {
    return __builtin_bit_cast(half2t, __builtin_amdgcn_cvt_pkrtz(a, b));
}
#define MFMA16(A, B, C) __builtin_amdgcn_mfma_f32_16x16x32_f16((A), (B), (C), 0, 0, 0)
union H8U { half8 v; half2t p[4]; };

__device__ __forceinline__ half8 cvt8(float4 a, float4 b) {
    H8U u;
    u.p[0] = pk16(a.x, a.y); u.p[1] = pk16(a.z, a.w);
    u.p[2] = pk16(b.x, b.y); u.p[3] = pk16(b.z, b.w);
    return u.v;
}
__device__ __forceinline__ floatx4 splat4(float a) { floatx4 r = {a, a, a, a}; return r; }

__global__
__attribute__((amdgpu_flat_work_group_size(256, 256), amdgpu_waves_per_eu(1, 1)))
void lstm_w4(
    const float* __restrict__ data,   // [B, T, I]
    const float* __restrict__ W_ih,   // [4H, I]
    const float* __restrict__ W_hh,   // [4H, H]
    const float* __restrict__ b_ih,   // [4H]
    const float* __restrict__ b_hh,   // [4H]
    float* __restrict__ out)          // [B, T, H] f32
{
    const int b   = blockIdx.x;
    const int t   = threadIdx.x;
    const int w   = t >> 6;    // wave 0..3; wave owns cols [32w, 32w+32)
    const int l   = t & 63;    // lane
    const int col = l & 15;    // N-col within a 16-wide tile
    const int kg  = l >> 4;    // k-group / C-row group

    // ---- weights static in registers (B-operands -> AGPR half) ----
    // gates 0(i),1(f),3(o): sigma(x)=rcp(1+exp2(-log2e*x))
    // gate 2(g):            tanh(x) via e=exp2(-2log2e*x), (1-e)*rcp(1+e)
    half8 bfh[4][2][4];   // Whh: gate x tile x 4 K-slices (K=128)
    half8 bfx[4][2][2];   // Wih: gate x tile x 2 K-slices (K=64)
    float bs[4][2];       // scaled bias
#pragma unroll
    for (int g = 0; g < 4; ++g) {
        const float sc = (g == 2) ? -2.8853900817779268f : -1.4426950408889634f;
#pragma unroll
        for (int tau = 0; tau < 2; ++tau) {
            const int row = 128 * g + 32 * w + 16 * tau + col;
            bs[g][tau] = sc * (b_ih[row] + b_hh[row]);
            const float* wh = W_hh + (size_t)row * Hh;
            const float* wi = W_ih + (size_t)row * Ii;
#pragma unroll
            for (int s = 0; s < 4; ++s) {
                const float* src = wh + 32 * s + 8 * kg;
                const float4 f0 = ((const float4*)src)[0];
                const float4 f1 = ((const float4*)src)[1];
                H8U u;
                u.p[0] = pk16(sc * f0.x, sc * f0.y); u.p[1] = pk16(sc * f0.z, sc * f0.w);
                u.p[2] = pk16(sc * f1.x, sc * f1.y); u.p[3] = pk16(sc * f1.z, sc * f1.w);
                bfh[g][tau][s] = u.v;
            }
#pragma unroll
            for (int s = 0; s < 2; ++s) {
                const float* src = wi + 32 * s + 8 * kg;
                const float4 f0 = ((const float4*)src)[0];
                const float4 f1 = ((const float4*)src)[1];
                H8U u;
                u.p[0] = pk16(sc * f0.x, sc * f0.y); u.p[1] = pk16(sc * f0.z, sc * f0.w);
                u.p[2] = pk16(sc * f1.x, sc * f1.y); u.p[3] = pk16(sc * f1.z, sc * f1.w);
                bfx[g][tau][s] = u.v;
            }
        }
    }

    __shared__ __align__(16) _Float16 hb[2][Hh];   // h double buffer
    if (t < Hh) hb[0][t] = (_Float16)0.0f;         // h0 = 0

    const float* xp  = data + (size_t)b * Tt * Ii;
    float*       opr = out  + (size_t)b * Tt * Hh + 32 * w + col;

    // x chunk staging: lane reads x[t0 + col][32*s2 + 8*kg + j], j=0..7
    const float* xbase = xp + (size_t)(l & 15) * Ii + 8 * kg;
    float4 xf0 = *(const float4*)(xbase);
    float4 xf1 = *(const float4*)(xbase + 4);
    float4 xf2 = *(const float4*)(xbase + 32);
    float4 xf3 = *(const float4*)(xbase + 36);

    // ---- prologue: chunk-0 xw (16 MFMA), chunk-1 x loads in flight ----
    half8 ax0 = cvt8(xf0, xf1);
    half8 ax1 = cvt8(xf2, xf3);
    xf0 = *(const float4*)(xbase + CH * Ii);
    xf1 = *(const float4*)(xbase + CH * Ii + 4);
    xf2 = *(const float4*)(xbase + CH * Ii + 32);
    xf3 = *(const float4*)(xbase + CH * Ii + 36);
    floatx4 xw_i0 = MFMA16(ax0, bfx[0][0][0], splat4(bs[0][0]));
    floatx4 xw_f0 = MFMA16(ax0, bfx[1][0][0], splat4(bs[1][0]));
    floatx4 xw_g0 = MFMA16(ax0, bfx[2][0][0], splat4(bs[2][0]));
    floatx4 xw_o0 = MFMA16(ax0, bfx[3][0][0], splat4(bs[3][0]));
    floatx4 xw_i1 = MFMA16(ax0, bfx[0][1][0], splat4(bs[0][1]));
    floatx4 xw_f1 = MFMA16(ax0, bfx[1][1][0], splat4(bs[1][1]));
    floatx4 xw_g1 = MFMA16(ax0, bfx[2][1][0], splat4(bs[2][1]));
    floatx4 xw_o1 = MFMA16(ax0, bfx[3][1][0], splat4(bs[3][1]));
    xw_i0 = MFMA16(ax1, bfx[0][0][1], xw_i0);
    xw_f0 = MFMA16(ax1, bfx[1][0][1], xw_f0);
    xw_g0 = MFMA16(ax1, bfx[2][0][1], xw_g0);
    xw_o0 = MFMA16(ax1, bfx[3][0][1], xw_o0);
    xw_i1 = MFMA16(ax1, bfx[0][1][1], xw_i1);
    xw_f1 = MFMA16(ax1, bfx[1][1][1], xw_f1);
    xw_g1 = MFMA16(ax1, bfx[2][1][1], xw_g1);
    xw_o1 = MFMA16(ax1, bfx[3][1][1], xw_o1);

    half8 nax0, nax1;                 // next chunk's A fragments
    floatx4 nxw_i0, nxw_f0, nxw_g0, nxw_o0, nxw_i1, nxw_f1, nxw_g1, nxw_o1;

    float c0 = 0.0f, c1 = 0.0f;
    __syncthreads();   // h0 visible (one full drain, outside the loop)

#pragma unroll 1
    for (int n = 0; n < NCH; ++n) {
        const float* xb2 = xbase + (size_t)((n + 2 < NCH) ? n + 2 : NCH - 1) * CH * Ii;

        // step s = 16n + 4P + R; h buffer parity = R&1 (16n+4P even).
        // f,g chains (both tiles) complete first; i next; o trails so the
        // exposed post-MFMA tail is just sigma(o)*tc + pack/write.
#define STEP(P, R, CUR, XTRA)                                                 \
        {                                                                     \
            const _Float16* hbase = &hb[CUR][8 * kg];                         \
            const half8 ah0 = *(const half8*)(hbase);                         \
            const half8 ah1 = *(const half8*)(hbase + 32);                    \
            const half8 ah2 = *(const half8*)(hbase + 64);                    \
            const half8 ah3 = *(const half8*)(hbase + 96);                    \
            XTRA;                                                             \
            floatx4 qf0 = MFMA16(ah0, bfh[1][0][0], xw_f0);                   \
            floatx4 qg0 = MFMA16(ah0, bfh[2][0][0], xw_g0);                   \
            floatx4 qf1 = MFMA16(ah0, bfh[1][1][0], xw_f1);                   \
            floatx4 qg1 = MFMA16(ah0, bfh[2][1][0], xw_g1);                   \
            qf0 = MFMA16(ah1, bfh[1][0][1], qf0);                             \
            qg0 = MFMA16(ah1, bfh[2][0][1], qg0);                             \
            qf1 = MFMA16(ah1, bfh[1][1][1], qf1);                             \
            qg1 = MFMA16(ah1, bfh[2][1][1], qg1);                             \
            floatx4 qi0 = MFMA16(ah0, bfh[0][0][0], xw_i0);                   \
            floatx4 qi1 = MFMA16(ah0, bfh[0][1][0], xw_i1);                   \
            qf0 = MFMA16(ah2, bfh[1][0][2], qf0);                             \
            qg0 = MFMA16(ah2, bfh[2][0][2], qg0);                             \
            qf1 = MFMA16(ah2, bfh[1][1][2], qf1);                             \
            qg1 = MFMA16(ah2, bfh[2][1][2], qg1);                             \
            qi0 = MFMA16(ah1, bfh[0][0][1], qi0);                             \
            qi1 = MFMA16(ah1, bfh[0][1][1], qi1);                             \
            qf0 = MFMA16(ah3, bfh[1][0][3], qf0);                             \
            qg0 = MFMA16(ah3, bfh[2][0][3], qg0);                             \
            qf1 = MFMA16(ah3, bfh[1][1][3], qf1);                             \
            qg1 = MFMA16(ah3, bfh[2][1][3], qg1);                             \
            floatx4 qo0 = MFMA16(ah0, bfh[3][0][0], xw_o0);                   \
            floatx4 qo1 = MFMA16(ah0, bfh[3][1][0], xw_o1);                   \
            qi0 = MFMA16(ah2, bfh[0][0][2], qi0);                             \
            qi1 = MFMA16(ah2, bfh[0][1][2], qi1);                             \
            const float fg0 = fast_rcp(1.0f + exp2_(qf0[R]));                 \
            const float eg0 = exp2_(qg0[R]);                                  \
            const float fg1 = fast_rcp(1.0f + exp2_(qf1[R]));                 \
            const float eg1 = exp2_(qg1[R]);                                  \
            qo0 = MFMA16(ah1, bfh[3][0][1], qo0);                             \
            qo1 = MFMA16(ah1, bfh[3][1][1], qo1);                             \
            const float fc0 = fg0 * c0;                                       \
            const float gv0 = (1.0f - eg0) * fast_rcp(1.0f + eg0);            \
            const float fc1 = fg1 * c1;                                       \
            const float gv1 = (1.0f - eg1) * fast_rcp(1.0f + eg1);            \
            qi0 = MFMA16(ah3, bfh[0][0][3], qi0);                             \
            qi1 = MFMA16(ah3, bfh[0][1][3], qi1);                             \
            qo0 = MFMA16(ah2, bfh[3][0][2], qo0);                             \
            qo1 = MFMA16(ah2, bfh[3][1][2], qo1);                             \
            const float ig0 = fast_rcp(1.0f + exp2_(qi0[R]));                 \
            const float ig1 = fast_rcp(1.0f + exp2_(qi1[R]));                 \
            c0 = fmaf(ig0, gv0, fc0);                                         \
            c1 = fmaf(ig1, gv1, fc1);                                         \
            qo0 = MFMA16(ah3, bfh[3][0][3], qo0);                             \
            qo1 = MFMA16(ah3, bfh[3][1][3], qo1);                             \
            const float ec0 = exp2_(-2.8853900817779268f * c0);               \
            const float ec1 = exp2_(-2.8853900817779268f * c1);               \
            const float tc0 = (1.0f - ec0) * fast_rcp(1.0f + ec0);            \
            const float tc1 = (1.0f - ec1) * fast_rcp(1.0f + ec1);            \
            const float og0 = fast_rcp(1.0f + exp2_(qo0[R]));                 \
            const float og1 = fast_rcp(1.0f + exp2_(qo1[R]));                 \
            const float h0 = og0 * tc0;                                       \
            const float h1 = og1 * tc1;                                       \
            if (kg == (P)) {                                                  \
                hb[(CUR) ^ 1][32 * w + col]      = (_Float16)h0;              \
                hb[(CUR) ^ 1][32 * w + 16 + col] = (_Float16)h1;              \
                *opr       = h0;                                              \
                *(opr + 16) = h1;                                             \
            }                                                                 \
            opr += Hh;                                                        \
            asm volatile("s_waitcnt lgkmcnt(0)\n\ts_barrier" ::: "memory");   \
        }

        // phase P handles steps 4P..4P+3; c lineage hops lane-groups:
        // rotate c from group P-1 (or prev chunk's group 3) into group P.
        // Next-chunk xw-GEMM + loads spread one-or-two per XTRA slot.
#define PHASE(P, X0, X1, X2, X3)                                              \
        STEP(P, 0, 0, X0) STEP(P, 1, 1, X1) STEP(P, 2, 0, X2) STEP(P, 3, 1, X3)

        PHASE(0,
              (c0 = __shfl(c0, (l + 48) & 63), c1 = __shfl(c1, (l + 48) & 63),
               nax0 = cvt8(xf0, xf1)),
              nax1 = cvt8(xf2, xf3),
              (nxw_i0 = MFMA16(nax0, bfx[0][0][0], splat4(bs[0][0])),
               nxw_i1 = MFMA16(nax0, bfx[0][1][0], splat4(bs[0][1]))),
              (nxw_f0 = MFMA16(nax0, bfx[1][0][0], splat4(bs[1][0])),
               nxw_f1 = MFMA16(nax0, bfx[1][1][0], splat4(bs[1][1]))))
        PHASE(1,
              (c0 = __shfl(c0, (l + 48) & 63), c1 = __shfl(c1, (l + 48) & 63),
               nxw_g0 = MFMA16(nax0, bfx[2][0][0], splat4(bs[2][0]))),
              (nxw_g1 = MFMA16(nax0, bfx[2][1][0], splat4(bs[2][1])),
               nxw_o0 = MFMA16(nax0, bfx[3][0][0], splat4(bs[3][0]))),
              (nxw_o1 = MFMA16(nax0, bfx[3][1][0], splat4(bs[3][1])),
               nxw_i0 = MFMA16(nax1, bfx[0][0][1], nxw_i0)),
              (nxw_i1 = MFMA16(nax1, bfx[0][1][1], nxw_i1),
               nxw_f0 = MFMA16(nax1, bfx[1][0][1], nxw_f0)))
        PHASE(2,
              (c0 = __shfl(c0, (l + 48) & 63), c1 = __shfl(c1, (l + 48) & 63),
               nxw_f1 = MFMA16(nax1, bfx[1][1][1], nxw_f1)),
              (nxw_g0 = MFMA16(nax1, bfx[2][0][1], nxw_g0),
               nxw_g1 = MFMA16(nax1, bfx[2][1][1], nxw_g1)),
              (nxw_o0 = MFMA16(nax1, bfx[3][0][1], nxw_o0),
               nxw_o1 = MFMA16(nax1, bfx[3][1][1], nxw_o1)),
              (xf0 = *(const float4*)(xb2),
               xf1 = *(const float4*)(xb2 + 4)))
        PHASE(3,
              (c0 = __shfl(c0, (l + 48) & 63), c1 = __shfl(c1, (l + 48) & 63),
               xf2 = *(const float4*)(xb2 + 32)),
              xf3 = *(const float4*)(xb2 + 36),
              (void)0,
              (void)0)
#undef PHASE
#undef STEP

        xw_i0 = nxw_i0; xw_f0 = nxw_f0; xw_g0 = nxw_g0; xw_o0 = nxw_o0;
        xw_i1 = nxw_i1; xw_f1 = nxw_f1; xw_g1 = nxw_g1; xw_o1 = nxw_o1;
    }
}

extern "C" void kernel_launch(void* const* d_in, const int* in_sizes, int n_in,
                              void* d_out, int out_size, void* d_ws, size_t ws_size,
                              hipStream_t stream) {
    const float* data = (const float*)d_in[0];
    const float* W_ih = (const float*)d_in[1];
    const float* W_hh = (const float*)d_in[2];
    const float* b_ih = (const float*)d_in[3];
    const float* b_hh = (const float*)d_in[4];
    float* out = (float*)d_out;

    hipLaunchKernelGGL(lstm_w4, dim3(256), dim3(256), 0, stream,
                       data, W_ih, W_hh, b_ih, b_hh, out);
}

// Round 10
// 382.736 us; speedup vs baseline: 1.2428x; 1.2428x over previous
//
#include <hip/hip_runtime.h>

// LSTM B=256, T=1024, I=64, H=128. One block/batch row (256 blocks = 256 CUs).
// R18: i8 h-GEMM inside the PROVEN R10 shape (8 waves x 16 cols, in-register
// xw, no HBM ws), with the spill fixed by REGISTER DIET instead of asm:
//  - Budget forensics (R11-R17): 256 regs/wave total = 128 arch + 128 AGPR
//    (accum_offset). f16 B-fragments ride AGPR-side; i8 bqh (32) stays arch.
//    R15 arch demand ~136 -> ~8-reg loop spill -> 242MB/dispatch scratch.
//  - Cut 1: bfx (Wih fragments, 32 regs, used once/16 steps) -> LDS (64KB,
//    per-lane identity layout, 2x ds_read_b128 per gate at chunk top).
//  - Cut 2: xw kept as packed half16 (8 regs vs 32 f32; R16-proven numerics).
//    Arch demand ~110 < 128 -> no spill.
//  - A/B decision value: issue 620->~330 cyc/step in the 417us structure.
//    ~350-380us => step was partly issue-bound; ~430-460 => ~1000cyc serial
//    floor confirmed (structural ceiling, declare next round).
//  - i8 numerics unchanged from R13/R15/R16 (all passed, absmax 0.0039):
//    h @ fixed scale 127, LDS bytes, W_hh per-row max-abs, lane-local
//    dequant, exp2 consts folded.

typedef _Float16 half8  __attribute__((ext_vector_type(8)));
typedef _Float16 half16 __attribute__((ext_vector_type(16)));
typedef _Float16 half2t __attribute__((ext_vector_type(2)));
typedef float  floatx4  __attribute__((ext_vector_type(4)));
typedef int    intx4   __attribute__((ext_vector_type(4)));

constexpr int Tt = 1024;
constexpr int Ii = 64;
constexpr int Hh = 128;
constexpr int CH = 16;          // timesteps per x chunk-GEMM
constexpr int NCH = Tt / CH;    // 64 chunks

__device__ __forceinline__ float fast_rcp(float x) { return __builtin_amdgcn_rcpf(x); }
__device__ __forceinline__ float exp2_(float x)    { return __builtin_amdgcn_exp2f(x); }
__device__ __forceinline__ half2t pk16(float a, float b) {
    return __builtin_bit_cast(half2t, __builtin_amdgcn_cvt_pkrtz(a, b));
}
#define MFMA16(A, B, C) __builtin_amdgcn_mfma_f32_16x16x32_f16((A), (B), (C), 0, 0, 0)
#define MFMAI8(A, B, C) __builtin_amdgcn_mfma_i32_16x16x64_i8((A), (B), (C), 0, 0, 0)
union H8U { half8 v; half2t p[4]; };

__device__ __forceinline__ half8 cvt8(float4 a, float4 b) {
    H8U u;
    u.p[0] = pk16(a.x, a.y); u.p[1] = pk16(a.z, a.w);
    u.p[2] = pk16(b.x, b.y); u.p[3] = pk16(b.z, b.w);
    return u.v;
}
__device__ __forceinline__ floatx4 splat4(float a) { floatx4 r = {a, a, a, a}; return r; }

// register-only i8x4 pack: low byte = s[0] (little-endian, matches LDS bytes)
__device__ __forceinline__ int pkq4(const float* s, float qs) {
    const int a = (int)rintf(s[0] * qs) & 255;
    const int b = (int)rintf(s[1] * qs) & 255;
    const int c = (int)rintf(s[2] * qs) & 255;
    const int d = (int)rintf(s[3] * qs) & 255;
    return a | (b << 8) | (c << 16) | (d << 24);
}

__global__ __launch_bounds__(512, 1) void lstm_i8r(
    const float* __restrict__ data,   // [B, T, I]
    const float* __restrict__ W_ih,   // [4H, I]
    const float* __restrict__ W_hh,   // [4H, H]
    const float* __restrict__ b_ih,   // [4H]
    const float* __restrict__ b_hh,   // [4H]
    float* __restrict__ out)          // [B, T, H] f32
{
    const int b   = blockIdx.x;
    const int t   = threadIdx.x;
    const int w   = t >> 6;    // wave 0..7
    const int l   = t & 63;    // lane
    const int col = l & 15;    // N-col == hidden unit offset within wave's 16
    const int kg  = l >> 4;    // k-group / C-row group

    // LDS: Wih fragments (64KB, per-lane identity layout) + h i8 dbuf (256B)
    __shared__ __align__(16) half8 wihf[8][512];          // [g*2+s][thread]
    __shared__ __align__(16) signed char hbq[2][Hh];
    if (t < Hh) hbq[0][t] = 0;        // h0 = 0

    // gates 0(i),1(f),3(o): sigma(x)=rcp(1+exp2(-log2e*x))
    // gate 2(g):            tanh(x) via e=exp2(-2log2e*x), (1-e)*rcp(1+e)
    intx4 bqh[4][2];   // Whh int8: 4 gates x 2 K-slices (K=128 as 2x64)
    float dqh[4];      // per-gate-row dequant scale (sc folded)
    float bs[4];       // scaled bias (x chunk-GEMM C-init)
#pragma unroll
    for (int g = 0; g < 4; ++g) {
        const float sc = (g == 2) ? -2.8853900817779268f : -1.4426950408889634f;
        const int row = 128 * g + 16 * w + col;
        bs[g] = sc * (b_ih[row] + b_hh[row]);
        const float* wh = W_hh + (size_t)row * Hh;
        const float* wi = W_ih + (size_t)row * Ii;
        // Whh: row max-abs then i8 quantize (register-only pack)
        float mw = 1e-20f;
#pragma unroll
        for (int k = 0; k < Hh; k += 4) {
            const float4 f = *(const float4*)(wh + k);
            mw = fmaxf(mw, fmaxf(fmaxf(fabsf(f.x), fabsf(f.y)),
                                 fmaxf(fabsf(f.z), fabsf(f.w))));
        }
        const float qs = 127.f / mw;
        dqh[g] = sc * mw * (1.f / (127.f * 127.f));
#pragma unroll
        for (int s = 0; s < 2; ++s) {
            const float* src = wh + 64 * s + 16 * kg;
            intx4 q;
            q[0] = pkq4(src + 0,  qs);
            q[1] = pkq4(src + 4,  qs);
            q[2] = pkq4(src + 8,  qs);
            q[3] = pkq4(src + 12, qs);
            bqh[g][s] = q;
        }
        // Wih fragments (sc folded) -> LDS, per-lane identity slot
#pragma unroll
        for (int s = 0; s < 2; ++s) {
            const float* src = wi + 32 * s + 8 * kg;
            const float4 f0 = ((const float4*)src)[0];
            const float4 f1 = ((const float4*)src)[1];
            H8U u;
            u.p[0] = pk16(sc * f0.x, sc * f0.y); u.p[1] = pk16(sc * f0.z, sc * f0.w);
            u.p[2] = pk16(sc * f1.x, sc * f1.y); u.p[3] = pk16(sc * f1.z, sc * f1.w);
            wihf[g * 2 + s][t] = u.v;
        }
    }

    const float* xp  = data + (size_t)b * Tt * Ii;
    float*       opr = out  + (size_t)b * Tt * Hh + 16 * w + col;

    // x chunk staging: lane reads x[t0 + (l&15)][32*s2 + 8*kg + j], j=0..7
    const float* xbase = xp + (size_t)(l & 15) * Ii + 8 * kg;
    float4 xf0 = *(const float4*)(xbase);
    float4 xf1 = *(const float4*)(xbase + 4);
    float4 xf2 = *(const float4*)(xbase + 32);
    float4 xf3 = *(const float4*)(xbase + 36);

    float c = 0.0f;
    __syncthreads();   // h0 + wihf visible (one full drain, outside the loop)

#pragma unroll 1
    for (int n = 0; n < NCH; ++n) {
        // ---- chunk-GEMM: cw[g*4+R] = sc*(xW+bias), packed f16 (8 regs) ----
        half16 cw;
        {
            const half8 ax0 = cvt8(xf0, xf1);
            const half8 ax1 = cvt8(xf2, xf3);
            // prefetch next chunk's x under the GEMM
            const int nn = (n + 1 < NCH) ? (n + 1) : n;
            const float* xb2 = xbase + (size_t)nn * CH * Ii;
            xf0 = *(const float4*)(xb2);
            xf1 = *(const float4*)(xb2 + 4);
            xf2 = *(const float4*)(xb2 + 32);
            xf3 = *(const float4*)(xb2 + 36);
            // gates in 2 groups of 2 to cap transient registers
#pragma unroll
            for (int gp = 0; gp < 2; ++gp) {
                const int g0 = gp * 2, g1 = gp * 2 + 1;
                const half8 fA0 = wihf[g0 * 2 + 0][t];
                const half8 fA1 = wihf[g0 * 2 + 1][t];
                const half8 fB0 = wihf[g1 * 2 + 0][t];
                const half8 fB1 = wihf[g1 * 2 + 1][t];
                floatx4 xa = MFMA16(ax0, fA0, splat4(bs[g0]));
                floatx4 xb = MFMA16(ax0, fB0, splat4(bs[g1]));
                xa = MFMA16(ax1, fA1, xa);
                xb = MFMA16(ax1, fB1, xb);
                cw[g0 * 4 + 0] = (_Float16)xa[0];
                cw[g0 * 4 + 1] = (_Float16)xa[1];
                cw[g0 * 4 + 2] = (_Float16)xa[2];
                cw[g0 * 4 + 3] = (_Float16)xa[3];
                cw[g1 * 4 + 0] = (_Float16)xb[0];
                cw[g1 * 4 + 1] = (_Float16)xb[1];
                cw[g1 * 4 + 2] = (_Float16)xb[2];
                cw[g1 * 4 + 3] = (_Float16)xb[3];
            }
        }

        // step s = 16n + 4P + R; h buffer parity = R&1 (16n+4P even).
        // f,g,i 2-deep i8 chains first; o trails so the exposed tail is just
        // sigma(o)*tc + quant/pack/write.
#define STEP(P, R, CUR, XTRA)                                                 \
        {                                                                     \
            const signed char* hbase = &hbq[CUR][16 * kg];                    \
            const intx4 ah0 = *(const intx4*)(hbase);                         \
            const intx4 ah1 = *(const intx4*)(hbase + 64);                    \
            XTRA;                                                             \
            __builtin_amdgcn_s_setprio(1);                                    \
            const intx4 z4 = {0, 0, 0, 0};                                    \
            intx4 qf = MFMAI8(ah0, bqh[1][0], z4);   /* f */                  \
            intx4 qg = MFMAI8(ah0, bqh[2][0], z4);   /* g */                  \
            intx4 qi = MFMAI8(ah0, bqh[0][0], z4);   /* i */                  \
            qf = MFMAI8(ah1, bqh[1][1], qf);                                  \
            qg = MFMAI8(ah1, bqh[2][1], qg);                                  \
            qi = MFMAI8(ah1, bqh[0][1], qi);                                  \
            intx4 qo = MFMAI8(ah0, bqh[3][0], z4);   /* o */                  \
            const float fg = fast_rcp(1.0f + exp2_(fmaf((float)qf[R], dqh[1], (float)cw[4 + (R)]))); \
            const float eg = exp2_(fmaf((float)qg[R], dqh[2], (float)cw[8 + (R)])); \
            qo = MFMAI8(ah1, bqh[3][1], qo);                                  \
            const float fc = fg * c;                                          \
            const float gv = (1.0f - eg) * fast_rcp(1.0f + eg);               \
            const float ig = fast_rcp(1.0f + exp2_(fmaf((float)qi[R], dqh[0], (float)cw[0 + (R)]))); \
            __builtin_amdgcn_s_setprio(0);                                    \
            c = fmaf(ig, gv, fc);                                             \
            const float ec = exp2_(-2.8853900817779268f * c);                 \
            const float tc = (1.0f - ec) * fast_rcp(1.0f + ec);               \
            const float og = fast_rcp(1.0f + exp2_(fmaf((float)qo[R], dqh[3], (float)cw[12 + (R)]))); \
            const float h  = og * tc;                                         \
            if (kg == (P)) {                                                  \
                hbq[(CUR) ^ 1][16 * w + col] =                                \
                    (signed char)(int)rintf(h * 127.f);                       \
                *opr = h;                                                     \
            }                                                                 \
            opr += Hh;                                                        \
            asm volatile("s_waitcnt lgkmcnt(0)\n\ts_barrier" ::: "memory");   \
        }

        // phase P handles steps 4P..4P+3; c lineage hops lane-groups:
        // rotate c from group P-1 (or prev chunk's group 3) into group P.
#define PHASE(P)                                                              \
        STEP(P, 0, 0, c = __shfl(c, (l + 48) & 63))                           \
        STEP(P, 1, 1, (void)0) STEP(P, 2, 0, (void)0) STEP(P, 3, 1, (void)0)

        PHASE(0) PHASE(1) PHASE(2) PHASE(3)
#undef PHASE
#undef STEP
    }
}

extern "C" void kernel_launch(void* const* d_in, const int* in_sizes, int n_in,
                              void* d_out, int out_size, void* d_ws, size_t ws_size,
                              hipStream_t stream) {
    const float* data = (const float*)d_in[0];
    const float* W_ih = (const float*)d_in[1];
    const float* W_hh = (const float*)d_in[2];
    const float* b_ih = (const float*)d_in[3];
    const float* b_hh = (const float*)d_in[4];
    float* out = (float*)d_out;

    hipLaunchKernelGGL(lstm_i8r, dim3(256), dim3(512), 0, stream,
                       data, W_ih, W_hh, b_ih, b_hh, out);
}

// Round 11
// 379.589 us; speedup vs baseline: 1.2531x; 1.0083x over previous
//
#include <hip/hip_runtime.h>

// LSTM B=256, T=1024, I=64, H=128. One block/batch row (256 blocks = 256 CUs).
// R19 = R18 (i8 h-GEMM, bfx in LDS, VGPR 64, no spill, 383us) + VALU/latency
// diet on the step critical path:
//  - Evidence: VALUBusy ~430cyc/step in BOTH f16(R10) and i8(R18) kernels
//    while MFMA halved -> VALU (dominated by 10 quarter-rate transcendentals)
//    is now the largest step component (437 > 257 MFMA > ~200 sync).
//  1. rcp merging: sig(i)*tanh(g) = (1-eg)*rcp((1+ei)(1+eg)); h = sig(o)*
//     tanh(c) = (1-ec)*rcp((1+eo)(1+ec)). 10 trans -> 8 (5 exp + 3 rcp).
//  2. parallel K-halves: per gate 2 independent MFMAs (C=0) + scalar i32 add
//     of the [R] elements instead of a 2-deep dependent chain (-~20cyc/gate
//     of exposed MFMA latency; all 8 MFMAs issue back-to-back).
//  3. xw kept in f32 (4x floatx4): -4 v_cvt per step, -16 cvt per chunk
//     (VGPR headroom: 64 -> ~90 of 128+).
//  - i8 numerics unchanged (absmax 0.0039 passing): h @ fixed scale 127, LDS
//    bytes; W_hh per-row max-abs i8, lane-local dequant; exp2 consts folded.

typedef _Float16 half8  __attribute__((ext_vector_type(8)));
typedef _Float16 half2t __attribute__((ext_vector_type(2)));
typedef float  floatx4  __attribute__((ext_vector_type(4)));
typedef int    intx4   __attribute__((ext_vector_type(4)));

constexpr int Tt = 1024;
constexpr int Ii = 64;
constexpr int Hh = 128;
constexpr int CH = 16;          // timesteps per x chunk-GEMM
constexpr int NCH = Tt / CH;    // 64 chunks

__device__ __forceinline__ float fast_rcp(float x) { return __builtin_amdgcn_rcpf(x); }
__device__ __forceinline__ float exp2_(float x)    { return __builtin_amdgcn_exp2f(x); }
__device__ __forceinline__ half2t pk16(float a, float b) {
    return __builtin_bit_cast(half2t, __builtin_amdgcn_cvt_pkrtz(a, b));
}
#define MFMA16(A, B, C) __builtin_amdgcn_mfma_f32_16x16x32_f16((A), (B), (C), 0, 0, 0)
#define MFMAI8(A, B, C) __builtin_amdgcn_mfma_i32_16x16x64_i8((A), (B), (C), 0, 0, 0)
union H8U { half8 v; half2t p[4]; };

__device__ __forceinline__ half8 cvt8(float4 a, float4 b) {
    H8U u;
    u.p[0] = pk16(a.x, a.y); u.p[1] = pk16(a.z, a.w);
    u.p[2] = pk16(b.x, b.y); u.p[3] = pk16(b.z, b.w);
    return u.v;
}
__device__ __forceinline__ floatx4 splat4(float a) { floatx4 r = {a, a, a, a}; return r; }

// register-only i8x4 pack: low byte = s[0] (little-endian, matches LDS bytes)
__device__ __forceinline__ int pkq4(const float* s, float qs) {
    const int a = (int)rintf(s[0] * qs) & 255;
    const int b = (int)rintf(s[1] * qs) & 255;
    const int c = (int)rintf(s[2] * qs) & 255;
    const int d = (int)rintf(s[3] * qs) & 255;
    return a | (b << 8) | (c << 16) | (d << 24);
}

__global__ __launch_bounds__(512, 1) void lstm_i8r2(
    const float* __restrict__ data,   // [B, T, I]
    const float* __restrict__ W_ih,   // [4H, I]
    const float* __restrict__ W_hh,   // [4H, H]
    const float* __restrict__ b_ih,   // [4H]
    const float* __restrict__ b_hh,   // [4H]
    float* __restrict__ out)          // [B, T, H] f32
{
    const int b   = blockIdx.x;
    const int t   = threadIdx.x;
    const int w   = t >> 6;    // wave 0..7
    const int l   = t & 63;    // lane
    const int col = l & 15;    // N-col == hidden unit offset within wave's 16
    const int kg  = l >> 4;    // k-group / C-row group

    // LDS: Wih fragments (64KB, per-lane identity layout) + h i8 dbuf (256B)
    __shared__ __align__(16) half8 wihf[8][512];          // [g*2+s][thread]
    __shared__ __align__(16) signed char hbq[2][Hh];
    if (t < Hh) hbq[0][t] = 0;        // h0 = 0

    // gates 0(i),1(f),3(o): sigma(x)=rcp(1+exp2(-log2e*x))
    // gate 2(g):            tanh(x) via e=exp2(-2log2e*x), (1-e)*rcp(1+e)
    intx4 bqh[4][2];   // Whh int8: 4 gates x 2 K-slices (K=128 as 2x64)
    float dqh[4];      // per-gate-row dequant scale (sc folded)
    float bs[4];       // scaled bias (x chunk-GEMM C-init)
#pragma unroll
    for (int g = 0; g < 4; ++g) {
        const float sc = (g == 2) ? -2.8853900817779268f : -1.4426950408889634f;
        const int row = 128 * g + 16 * w + col;
        bs[g] = sc * (b_ih[row] + b_hh[row]);
        const float* wh = W_hh + (size_t)row * Hh;
        const float* wi = W_ih + (size_t)row * Ii;
        // Whh: row max-abs then i8 quantize (register-only pack)
        float mw = 1e-20f;
#pragma unroll
        for (int k = 0; k < Hh; k += 4) {
            const float4 f = *(const float4*)(wh + k);
            mw = fmaxf(mw, fmaxf(fmaxf(fabsf(f.x), fabsf(f.y)),
                                 fmaxf(fabsf(f.z), fabsf(f.w))));
        }
        const float qs = 127.f / mw;
        dqh[g] = sc * mw * (1.f / (127.f * 127.f));
#pragma unroll
        for (int s = 0; s < 2; ++s) {
            const float* src = wh + 64 * s + 16 * kg;
            intx4 q;
            q[0] = pkq4(src + 0,  qs);
            q[1] = pkq4(src + 4,  qs);
            q[2] = pkq4(src + 8,  qs);
            q[3] = pkq4(src + 12, qs);
            bqh[g][s] = q;
        }
        // Wih fragments (sc folded) -> LDS, per-lane identity slot
#pragma unroll
        for (int s = 0; s < 2; ++s) {
            const float* src = wi + 32 * s + 8 * kg;
            const float4 f0 = ((const float4*)src)[0];
            const float4 f1 = ((const float4*)src)[1];
            H8U u;
            u.p[0] = pk16(sc * f0.x, sc * f0.y); u.p[1] = pk16(sc * f0.z, sc * f0.w);
            u.p[2] = pk16(sc * f1.x, sc * f1.y); u.p[3] = pk16(sc * f1.z, sc * f1.w);
            wihf[g * 2 + s][t] = u.v;
        }
    }

    const float* xp  = data + (size_t)b * Tt * Ii;
    float*       opr = out  + (size_t)b * Tt * Hh + 16 * w + col;

    // x chunk staging: lane reads x[t0 + (l&15)][32*s2 + 8*kg + j], j=0..7
    const float* xbase = xp + (size_t)(l & 15) * Ii + 8 * kg;
    float4 xf0 = *(const float4*)(xbase);
    float4 xf1 = *(const float4*)(xbase + 4);
    float4 xf2 = *(const float4*)(xbase + 32);
    float4 xf3 = *(const float4*)(xbase + 36);

    float c = 0.0f;
    __syncthreads();   // h0 + wihf visible (one full drain, outside the loop)

#pragma unroll 1
    for (int n = 0; n < NCH; ++n) {
        // ---- chunk-GEMM: xw[g] = sc*(xW+bias) for steps t0..t0+15 (f32) ----
        floatx4 xw0, xw1, xw2, xw3;
        {
            const half8 ax0 = cvt8(xf0, xf1);
            const half8 ax1 = cvt8(xf2, xf3);
            // prefetch next chunk's x under the GEMM
            const int nn = (n + 1 < NCH) ? (n + 1) : n;
            const float* xb2 = xbase + (size_t)nn * CH * Ii;
            xf0 = *(const float4*)(xb2);
            xf1 = *(const float4*)(xb2 + 4);
            xf2 = *(const float4*)(xb2 + 32);
            xf3 = *(const float4*)(xb2 + 36);
            const half8 fA0 = wihf[0][t], fA1 = wihf[1][t];
            const half8 fB0 = wihf[2][t], fB1 = wihf[3][t];
            const half8 fC0 = wihf[4][t], fC1 = wihf[5][t];
            const half8 fD0 = wihf[6][t], fD1 = wihf[7][t];
            xw0 = MFMA16(ax0, fA0, splat4(bs[0]));
            xw1 = MFMA16(ax0, fB0, splat4(bs[1]));
            xw2 = MFMA16(ax0, fC0, splat4(bs[2]));
            xw3 = MFMA16(ax0, fD0, splat4(bs[3]));
            xw0 = MFMA16(ax1, fA1, xw0);
            xw1 = MFMA16(ax1, fB1, xw1);
            xw2 = MFMA16(ax1, fC1, xw2);
            xw3 = MFMA16(ax1, fD1, xw3);
        }

        // step s = 16n + 4P + R; h buffer parity = R&1 (16n+4P even).
        // 8 independent i8 MFMAs (parallel K-halves, C=0), scalar i32 add of
        // the [R] elements; merged-rcp activations (5 exp + 3 rcp).
#define STEP(P, R, CUR, XTRA)                                                 \
        {                                                                     \
            const signed char* hbase = &hbq[CUR][16 * kg];                    \
            const intx4 ah0 = *(const intx4*)(hbase);                         \
            const intx4 ah1 = *(const intx4*)(hbase + 64);                    \
            XTRA;                                                             \
            __builtin_amdgcn_s_setprio(1);                                    \
            const intx4 z4 = {0, 0, 0, 0};                                    \
            intx4 qfA = MFMAI8(ah0, bqh[1][0], z4);   /* f lo */              \
            intx4 qgA = MFMAI8(ah0, bqh[2][0], z4);   /* g lo */              \
            intx4 qiA = MFMAI8(ah0, bqh[0][0], z4);   /* i lo */              \
            intx4 qfB = MFMAI8(ah1, bqh[1][1], z4);   /* f hi */              \
            intx4 qgB = MFMAI8(ah1, bqh[2][1], z4);   /* g hi */              \
            intx4 qiB = MFMAI8(ah1, bqh[0][1], z4);   /* i hi */              \
            intx4 qoA = MFMAI8(ah0, bqh[3][0], z4);   /* o lo */              \
            intx4 qoB = MFMAI8(ah1, bqh[3][1], z4);   /* o hi */              \
            const float e_f = exp2_(fmaf((float)(qfA[R] + qfB[R]), dqh[1], xw1[R])); \
            const float e_g = exp2_(fmaf((float)(qgA[R] + qgB[R]), dqh[2], xw2[R])); \
            const float e_i = exp2_(fmaf((float)(qiA[R] + qiB[R]), dqh[0], xw0[R])); \
            __builtin_amdgcn_s_setprio(0);                                    \
            const float fg  = fast_rcp(1.0f + e_f);                           \
            const float igv = (1.0f - e_g) *                                  \
                              fast_rcp((1.0f + e_i) * (1.0f + e_g));          \
            c = fmaf(fg, c, igv);                                             \
            const float e_o = exp2_(fmaf((float)(qoA[R] + qoB[R]), dqh[3], xw3[R])); \
            const float e_c = exp2_(-2.8853900817779268f * c);                \
            const float h   = (1.0f - e_c) *                                  \
                              fast_rcp((1.0f + e_o) * (1.0f + e_c));          \
            if (kg == (P)) {                                                  \
                hbq[(CUR) ^ 1][16 * w + col] =                                \
                    (signed char)(int)rintf(h * 127.f);                       \
                *opr = h;                                                     \
            }                                                                 \
            opr += Hh;                                                        \
            asm volatile("s_waitcnt lgkmcnt(0)\n\ts_barrier" ::: "memory");   \
        }

        // phase P handles steps 4P..4P+3; c lineage hops lane-groups:
        // rotate c from group P-1 (or prev chunk's group 3) into group P.
#define PHASE(P)                                                              \
        STEP(P, 0, 0, c = __shfl(c, (l + 48) & 63))                           \
        STEP(P, 1, 1, (void)0) STEP(P, 2, 0, (void)0) STEP(P, 3, 1, (void)0)

        PHASE(0) PHASE(1) PHASE(2) PHASE(3)
#undef PHASE
#undef STEP
    }
}

extern "C" void kernel_launch(void* const* d_in, const int* in_sizes, int n_in,
                              void* d_out, int out_size, void* d_ws, size_t ws_size,
                              hipStream_t stream) {
    const float* data = (const float*)d_in[0];
    const float* W_ih = (const float*)d_in[1];
    const float* W_hh = (const float*)d_in[2];
    const float* b_ih = (const float*)d_in[3];
    const float* b_hh = (const float*)d_in[4];
    float* out = (float*)d_out;

    hipLaunchKernelGGL(lstm_i8r2, dim3(256), dim3(512), 0, stream,
                       data, W_ih, W_hh, b_ih, b_hh, out);
}

// Round 12
// 375.877 us; speedup vs baseline: 1.2654x; 1.0099x over previous
//
#include <hip/hip_runtime.h>

// LSTM B=256, T=1024, I=64, H=128. One block/batch row (256 blocks = 256 CUs).
// R20 = R19 (i8 h-GEMM, merged-rcp acts, 379.6us) + chunk-GEMM re-spread:
//  - R18/R19 compute the next chunk's x-projection as a serial lump at chunk
//    top (8 LDS reads + 8 f16 MFMA + 4 global loads) because the spread was
//    dropped while fixing the R11-R15 spill. Spill is gone (VGPR 64/128),
//    so the spread is register-safe again (+~32 transient regs -> ~96).
//  - Spread layout (16 XTRA slots/chunk): cvt8 at P0R0/R1; wihf pair-reads
//    and paired f16 MFMAs alternate through P0R2..P2R1; x prefetch at
//    P2R2..P3R0. Also hides the 120cyc post-barrier ds_read under real work
//    in 12/16 steps (R9 measured the same spread worth ~11us on the f16 path).
//  - e_o hoisted above the c-fmaf (independent of c) -> shortens the
//    post-last-MFMA serial tail by ~16cyc.
//  - i8 numerics unchanged (absmax 0.0039): h @ fixed scale 127, LDS bytes,
//    W_hh per-row max-abs, lane-local dequant, exp2 consts folded,
//    merged-rcp activations (5 exp + 3 rcp).

typedef _Float16 half8  __attribute__((ext_vector_type(8)));
typedef _Float16 half2t __attribute__((ext_vector_type(2)));
typedef float  floatx4  __attribute__((ext_vector_type(4)));
typedef int    intx4   __attribute__((ext_vector_type(4)));

constexpr int Tt = 1024;
constexpr int Ii = 64;
constexpr int Hh = 128;
constexpr int CH = 16;          // timesteps per x chunk-GEMM
constexpr int NCH = Tt / CH;    // 64 chunks

__device__ __forceinline__ float fast_rcp(float x) { return __builtin_amdgcn_rcpf(x); }
__device__ __forceinline__ float exp2_(float x)    { return __builtin_amdgcn_exp2f(x); }
__device__ __forceinline__ half2t pk16(float a, float b) {
    return __builtin_bit_cast(half2t, __builtin_amdgcn_cvt_pkrtz(a, b));
}
#define MFMA16(A, B, C) __builtin_amdgcn_mfma_f32_16x16x32_f16((A), (B), (C), 0, 0, 0)
#define MFMAI8(A, B, C) __builtin_amdgcn_mfma_i32_16x16x64_i8((A), (B), (C), 0, 0, 0)
union H8U { half8 v; half2t p[4]; };

__device__ __forceinline__ half8 cvt8(float4 a, float4 b) {
    H8U u;
    u.p[0] = pk16(a.x, a.y); u.p[1] = pk16(a.z, a.w);
    u.p[2] = pk16(b.x, b.y); u.p[3] = pk16(b.z, b.w);
    return u.v;
}
__device__ __forceinline__ floatx4 splat4(float a) { floatx4 r = {a, a, a, a}; return r; }

// register-only i8x4 pack: low byte = s[0] (little-endian, matches LDS bytes)
__device__ __forceinline__ int pkq4(const float* s, float qs) {
    const int a = (int)rintf(s[0] * qs) & 255;
    const int b = (int)rintf(s[1] * qs) & 255;
    const int c = (int)rintf(s[2] * qs) & 255;
    const int d = (int)rintf(s[3] * qs) & 255;
    return a | (b << 8) | (c << 16) | (d << 24);
}

__global__ __launch_bounds__(512, 1) void lstm_i8r3(
    const float* __restrict__ data,   // [B, T, I]
    const float* __restrict__ W_ih,   // [4H, I]
    const float* __restrict__ W_hh,   // [4H, H]
    const float* __restrict__ b_ih,   // [4H]
    const float* __restrict__ b_hh,   // [4H]
    float* __restrict__ out)          // [B, T, H] f32
{
    const int b   = blockIdx.x;
    const int t   = threadIdx.x;
    const int w   = t >> 6;    // wave 0..7
    const int l   = t & 63;    // lane
    const int col = l & 15;    // N-col == hidden unit offset within wave's 16
    const int kg  = l >> 4;    // k-group / C-row group

    // LDS: Wih fragments (64KB, per-lane identity layout) + h i8 dbuf (256B)
    __shared__ __align__(16) half8 wihf[8][512];          // [g*2+s][thread]
    __shared__ __align__(16) signed char hbq[2][Hh];
    if (t < Hh) hbq[0][t] = 0;        // h0 = 0

    // gates 0(i),1(f),3(o): sigma(x)=rcp(1+exp2(-log2e*x))
    // gate 2(g):            tanh(x) via e=exp2(-2log2e*x), (1-e)*rcp(1+e)
    intx4 bqh[4][2];   // Whh int8: 4 gates x 2 K-slices (K=128 as 2x64)
    float dqh[4];      // per-gate-row dequant scale (sc folded)
    float bs[4];       // scaled bias (x chunk-GEMM C-init)
#pragma unroll
    for (int g = 0; g < 4; ++g) {
        const float sc = (g == 2) ? -2.8853900817779268f : -1.4426950408889634f;
        const int row = 128 * g + 16 * w + col;
        bs[g] = sc * (b_ih[row] + b_hh[row]);
        const float* wh = W_hh + (size_t)row * Hh;
        const float* wi = W_ih + (size_t)row * Ii;
        // Whh: row max-abs then i8 quantize (register-only pack)
        float mw = 1e-20f;
#pragma unroll
        for (int k = 0; k < Hh; k += 4) {
            const float4 f = *(const float4*)(wh + k);
            mw = fmaxf(mw, fmaxf(fmaxf(fabsf(f.x), fabsf(f.y)),
                                 fmaxf(fabsf(f.z), fabsf(f.w))));
        }
        const float qs = 127.f / mw;
        dqh[g] = sc * mw * (1.f / (127.f * 127.f));
#pragma unroll
        for (int s = 0; s < 2; ++s) {
            const float* src = wh + 64 * s + 16 * kg;
            intx4 q;
            q[0] = pkq4(src + 0,  qs);
            q[1] = pkq4(src + 4,  qs);
            q[2] = pkq4(src + 8,  qs);
            q[3] = pkq4(src + 12, qs);
            bqh[g][s] = q;
        }
        // Wih fragments (sc folded) -> LDS, per-lane identity slot
#pragma unroll
        for (int s = 0; s < 2; ++s) {
            const float* src = wi + 32 * s + 8 * kg;
            const float4 f0 = ((const float4*)src)[0];
            const float4 f1 = ((const float4*)src)[1];
            H8U u;
            u.p[0] = pk16(sc * f0.x, sc * f0.y); u.p[1] = pk16(sc * f0.z, sc * f0.w);
            u.p[2] = pk16(sc * f1.x, sc * f1.y); u.p[3] = pk16(sc * f1.z, sc * f1.w);
            wihf[g * 2 + s][t] = u.v;
        }
    }

    const float* xp  = data + (size_t)b * Tt * Ii;
    float*       opr = out  + (size_t)b * Tt * Hh + 16 * w + col;

    // x chunk staging: lane reads x[t0 + (l&15)][32*s2 + 8*kg + j], j=0..7
    const float* xbase = xp + (size_t)(l & 15) * Ii + 8 * kg;
    float4 xf0 = *(const float4*)(xbase);
    float4 xf1 = *(const float4*)(xbase + 4);
    float4 xf2 = *(const float4*)(xbase + 32);
    float4 xf3 = *(const float4*)(xbase + 36);

    // ---- prologue: chunk-0 xw lump, chunk-1 x loads in flight under it ----
    floatx4 xw0, xw1, xw2, xw3;
    {
        const half8 ax0 = cvt8(xf0, xf1);
        const half8 ax1 = cvt8(xf2, xf3);
        xf0 = *(const float4*)(xbase + CH * Ii);
        xf1 = *(const float4*)(xbase + CH * Ii + 4);
        xf2 = *(const float4*)(xbase + CH * Ii + 32);
        xf3 = *(const float4*)(xbase + CH * Ii + 36);
        const half8 fA0 = wihf[0][t], fA1 = wihf[1][t];
        const half8 fB0 = wihf[2][t], fB1 = wihf[3][t];
        const half8 fC0 = wihf[4][t], fC1 = wihf[5][t];
        const half8 fD0 = wihf[6][t], fD1 = wihf[7][t];
        xw0 = MFMA16(ax0, fA0, splat4(bs[0]));
        xw1 = MFMA16(ax0, fB0, splat4(bs[1]));
        xw2 = MFMA16(ax0, fC0, splat4(bs[2]));
        xw3 = MFMA16(ax0, fD0, splat4(bs[3]));
        xw0 = MFMA16(ax1, fA1, xw0);
        xw1 = MFMA16(ax1, fB1, xw1);
        xw2 = MFMA16(ax1, fC1, xw2);
        xw3 = MFMA16(ax1, fD1, xw3);
    }

    half8 nax0, nax1, wA, wB;          // spread transients
    floatx4 nxw0, nxw1, nxw2, nxw3;    // next chunk's xW+bias accumulators

    float c = 0.0f;
    __syncthreads();   // h0 + wihf visible (one full drain, outside the loop)

#pragma unroll 1
    for (int n = 0; n < NCH; ++n) {
        const float* xb2 = xbase + (size_t)((n + 2 < NCH) ? n + 2 : NCH - 1) * CH * Ii;

        // step s = 16n + 4P + R; h buffer parity = R&1 (16n+4P even).
        // 8 independent i8 MFMAs (parallel K-halves, C=0), scalar i32 add of
        // [R] elems; merged-rcp activations; e_o hoisted above the c-chain.
#define STEP(P, R, CUR, XTRA)                                                 \
        {                                                                     \
            const signed char* hbase = &hbq[CUR][16 * kg];                    \
            const intx4 ah0 = *(const intx4*)(hbase);                         \
            const intx4 ah1 = *(const intx4*)(hbase + 64);                    \
            XTRA;                                                             \
            __builtin_amdgcn_s_setprio(1);                                    \
            const intx4 z4 = {0, 0, 0, 0};                                    \
            intx4 qfA = MFMAI8(ah0, bqh[1][0], z4);   /* f lo */              \
            intx4 qgA = MFMAI8(ah0, bqh[2][0], z4);   /* g lo */              \
            intx4 qiA = MFMAI8(ah0, bqh[0][0], z4);   /* i lo */              \
            intx4 qfB = MFMAI8(ah1, bqh[1][1], z4);   /* f hi */              \
            intx4 qgB = MFMAI8(ah1, bqh[2][1], z4);   /* g hi */              \
            intx4 qiB = MFMAI8(ah1, bqh[0][1], z4);   /* i hi */              \
            intx4 qoA = MFMAI8(ah0, bqh[3][0], z4);   /* o lo */              \
            intx4 qoB = MFMAI8(ah1, bqh[3][1], z4);   /* o hi */              \
            const float e_f = exp2_(fmaf((float)(qfA[R] + qfB[R]), dqh[1], xw1[R])); \
            const float e_g = exp2_(fmaf((float)(qgA[R] + qgB[R]), dqh[2], xw2[R])); \
            const float e_i = exp2_(fmaf((float)(qiA[R] + qiB[R]), dqh[0], xw0[R])); \
            const float e_o = exp2_(fmaf((float)(qoA[R] + qoB[R]), dqh[3], xw3[R])); \
            __builtin_amdgcn_s_setprio(0);                                    \
            const float fg  = fast_rcp(1.0f + e_f);                           \
            const float igv = (1.0f - e_g) *                                  \
                              fast_rcp((1.0f + e_i) * (1.0f + e_g));          \
            c = fmaf(fg, c, igv);                                             \
            const float e_c = exp2_(-2.8853900817779268f * c);                \
            const float h   = (1.0f - e_c) *                                  \
                              fast_rcp((1.0f + e_o) * (1.0f + e_c));          \
            if (kg == (P)) {                                                  \
                hbq[(CUR) ^ 1][16 * w + col] =                                \
                    (signed char)(int)rintf(h * 127.f);                       \
                *opr = h;                                                     \
            }                                                                 \
            opr += Hh;                                                        \
            asm volatile("s_waitcnt lgkmcnt(0)\n\ts_barrier" ::: "memory");   \
        }

        // phase P handles steps 4P..4P+3; c lineage hops lane-groups:
        // rotate c from group P-1 (or prev chunk's group 3) into group P.
        // Spread: next-chunk cvt/wihf-reads/f16-MFMAs/x-prefetch fill XTRA.
#define PHASE(P, X0, X1, X2, X3)                                              \
        STEP(P, 0, 0, X0) STEP(P, 1, 1, X1) STEP(P, 2, 0, X2) STEP(P, 3, 1, X3)

        PHASE(0,
              (c = __shfl(c, (l + 48) & 63), nax0 = cvt8(xf0, xf1)),
              nax1 = cvt8(xf2, xf3),
              (wA = wihf[0][t], wB = wihf[1][t]),
              (nxw0 = MFMA16(nax0, wA, splat4(bs[0])),
               nxw0 = MFMA16(nax1, wB, nxw0)))
        PHASE(1,
              (c = __shfl(c, (l + 48) & 63), wA = wihf[2][t], wB = wihf[3][t]),
              (nxw1 = MFMA16(nax0, wA, splat4(bs[1])),
               nxw1 = MFMA16(nax1, wB, nxw1)),
              (wA = wihf[4][t], wB = wihf[5][t]),
              (nxw2 = MFMA16(nax0, wA, splat4(bs[2])),
               nxw2 = MFMA16(nax1, wB, nxw2)))
        PHASE(2,
              (c = __shfl(c, (l + 48) & 63), wA = wihf[6][t], wB = wihf[7][t]),
              (nxw3 = MFMA16(nax0, wA, splat4(bs[3])),
               nxw3 = MFMA16(nax1, wB, nxw3)),
              (xf0 = *(const float4*)(xb2),
               xf1 = *(const float4*)(xb2 + 4)),
              (xf2 = *(const float4*)(xb2 + 32),
               xf3 = *(const float4*)(xb2 + 36)))
        PHASE(3,
              c = __shfl(c, (l + 48) & 63),
              (void)0,
              (void)0,
              (void)0)
#undef PHASE
#undef STEP

        xw0 = nxw0; xw1 = nxw1; xw2 = nxw2; xw3 = nxw3;
    }
}

extern "C" void kernel_launch(void* const* d_in, const int* in_sizes, int n_in,
                              void* d_out, int out_size, void* d_ws, size_t ws_size,
                              hipStream_t stream) {
    const float* data = (const float*)d_in[0];
    const float* W_ih = (const float*)d_in[1];
    const float* W_hh = (const float*)d_in[2];
    const float* b_ih = (const float*)d_in[3];
    const float* b_hh = (const float*)d_in[4];
    float* out = (float*)d_out;

    hipLaunchKernelGGL(lstm_i8r3, dim3(256), dim3(512), 0, stream,
                       data, W_ih, W_hh, b_ih, b_hh, out);
}

// Round 13
// 362.401 us; speedup vs baseline: 1.3125x; 1.0372x over previous
//
#include <hip/hip_runtime.h>

// LSTM B=256, T=1024, I=64, H=128. One block/batch row (256 blocks = 256 CUs).
// R21 = R20 (375.9us) with a consolidated op-diet under the CONTENTION model:
//  - Step budget @880cyc/SIMD: MFMA issue ~78, trans 2wavesx8x8~128 (both
//    lockstep waves serialize on the trans unit), other VALU ~140, ds/barrier
//    rest. Not one pipe saturated; cost is issued-op count + sync.
//  1. Chained 2-deep i8 MFMA restored (R18 style): parallel-K split's 4 adds
//     + 4 zero-inits are pure issue cost when dep-latency hides under the
//     partner wave. f,g,i chains first; o trails (tail = h-rcp only).
//  2. s_setprio removed: waves are barrier-lockstep (T5 null on lockstep,
//     m190).
//  3. c lineage stored pre-scaled (c' = -2log2e * c): gv folds the scale via
//     fmaf(e_g,2.885,-2.885); e_c = exp2(c') -- one chain mul removed.
//  4. Spread rebalance: x prefetch split 1 load/slot over P2R2..P3R1; wihf
//     reads + f16 MFMAs over P0R2..P2R1 -> 14/16 post-barrier ds_read
//     shadows covered (R20 left 3 naked).
//  - i8 numerics unchanged (absmax 0.0039 across R13-R20): h @ fixed scale
//    127, LDS bytes; W_hh per-row max-abs, lane-local dequant; exp2 folded;
//    merged-rcp activations (5 exp + 3 rcp).

typedef _Float16 half8  __attribute__((ext_vector_type(8)));
typedef _Float16 half2t __attribute__((ext_vector_type(2)));
typedef float  floatx4  __attribute__((ext_vector_type(4)));
typedef int    intx4   __attribute__((ext_vector_type(4)));

constexpr int Tt = 1024;
constexpr int Ii = 64;
constexpr int Hh = 128;
constexpr int CH = 16;          // timesteps per x chunk-GEMM
constexpr int NCH = Tt / CH;    // 64 chunks

__device__ __forceinline__ float fast_rcp(float x) { return __builtin_amdgcn_rcpf(x); }
__device__ __forceinline__ float exp2_(float x)    { return __builtin_amdgcn_exp2f(x); }
__device__ __forceinline__ half2t pk16(float a, float b) {
    return __builtin_bit_cast(half2t, __builtin_amdgcn_cvt_pkrtz(a, b));
}
#define MFMA16(A, B, C) __builtin_amdgcn_mfma_f32_16x16x32_f16((A), (B), (C), 0, 0, 0)
#define MFMAI8(A, B, C) __builtin_amdgcn_mfma_i32_16x16x64_i8((A), (B), (C), 0, 0, 0)
union H8U { half8 v; half2t p[4]; };

__device__ __forceinline__ half8 cvt8(float4 a, float4 b) {
    H8U u;
    u.p[0] = pk16(a.x, a.y); u.p[1] = pk16(a.z, a.w);
    u.p[2] = pk16(b.x, b.y); u.p[3] = pk16(b.z, b.w);
    return u.v;
}
__device__ __forceinline__ floatx4 splat4(float a) { floatx4 r = {a, a, a, a}; return r; }

// register-only i8x4 pack: low byte = s[0] (little-endian, matches LDS bytes)
__device__ __forceinline__ int pkq4(const float* s, float qs) {
    const int a = (int)rintf(s[0] * qs) & 255;
    const int b = (int)rintf(s[1] * qs) & 255;
    const int c = (int)rintf(s[2] * qs) & 255;
    const int d = (int)rintf(s[3] * qs) & 255;
    return a | (b << 8) | (c << 16) | (d << 24);
}

__global__ __launch_bounds__(512, 1) void lstm_i8r4(
    const float* __restrict__ data,   // [B, T, I]
    const float* __restrict__ W_ih,   // [4H, I]
    const float* __restrict__ W_hh,   // [4H, H]
    const float* __restrict__ b_ih,   // [4H]
    const float* __restrict__ b_hh,   // [4H]
    float* __restrict__ out)          // [B, T, H] f32
{
    const int b   = blockIdx.x;
    const int t   = threadIdx.x;
    const int w   = t >> 6;    // wave 0..7
    const int l   = t & 63;    // lane
    const int col = l & 15;    // N-col == hidden unit offset within wave's 16
    const int kg  = l >> 4;    // k-group / C-row group

    // LDS: Wih fragments (64KB, per-lane identity layout) + h i8 dbuf (256B)
    __shared__ __align__(16) half8 wihf[8][512];          // [g*2+s][thread]
    __shared__ __align__(16) signed char hbq[2][Hh];
    if (t < Hh) hbq[0][t] = 0;        // h0 = 0

    // gates 0(i),1(f),3(o): sigma(x)=rcp(1+exp2(-log2e*x))
    // gate 2(g):            tanh(x) via e=exp2(-2log2e*x), (1-e)*rcp(1+e)
    intx4 bqh[4][2];   // Whh int8: 4 gates x 2 K-slices (K=128 as 2x64)
    float dqh[4];      // per-gate-row dequant scale (sc folded)
    float bs[4];       // scaled bias (x chunk-GEMM C-init)
#pragma unroll
    for (int g = 0; g < 4; ++g) {
        const float sc = (g == 2) ? -2.8853900817779268f : -1.4426950408889634f;
        const int row = 128 * g + 16 * w + col;
        bs[g] = sc * (b_ih[row] + b_hh[row]);
        const float* wh = W_hh + (size_t)row * Hh;
        const float* wi = W_ih + (size_t)row * Ii;
        // Whh: row max-abs then i8 quantize (register-only pack)
        float mw = 1e-20f;
#pragma unroll
        for (int k = 0; k < Hh; k += 4) {
            const float4 f = *(const float4*)(wh + k);
            mw = fmaxf(mw, fmaxf(fmaxf(fabsf(f.x), fabsf(f.y)),
                                 fmaxf(fabsf(f.z), fabsf(f.w))));
        }
        const float qs = 127.f / mw;
        dqh[g] = sc * mw * (1.f / (127.f * 127.f));
#pragma unroll
        for (int s = 0; s < 2; ++s) {
            const float* src = wh + 64 * s + 16 * kg;
            intx4 q;
            q[0] = pkq4(src + 0,  qs);
            q[1] = pkq4(src + 4,  qs);
            q[2] = pkq4(src + 8,  qs);
            q[3] = pkq4(src + 12, qs);
            bqh[g][s] = q;
        }
        // Wih fragments (sc folded) -> LDS, per-lane identity slot
#pragma unroll
        for (int s = 0; s < 2; ++s) {
            const float* src = wi + 32 * s + 8 * kg;
            const float4 f0 = ((const float4*)src)[0];
            const float4 f1 = ((const float4*)src)[1];
            H8U u;
            u.p[0] = pk16(sc * f0.x, sc * f0.y); u.p[1] = pk16(sc * f0.z, sc * f0.w);
            u.p[2] = pk16(sc * f1.x, sc * f1.y); u.p[3] = pk16(sc * f1.z, sc * f1.w);
            wihf[g * 2 + s][t] = u.v;
        }
    }

    const float* xp  = data + (size_t)b * Tt * Ii;
    float*       opr = out  + (size_t)b * Tt * Hh + 16 * w + col;

    // x chunk staging: lane reads x[t0 + (l&15)][32*s2 + 8*kg + j], j=0..7
    const float* xbase = xp + (size_t)(l & 15) * Ii + 8 * kg;
    float4 xf0 = *(const float4*)(xbase);
    float4 xf1 = *(const float4*)(xbase + 4);
    float4 xf2 = *(const float4*)(xbase + 32);
    float4 xf3 = *(const float4*)(xbase + 36);

    // ---- prologue: chunk-0 xw lump, chunk-1 x loads in flight under it ----
    floatx4 xw0, xw1, xw2, xw3;
    {
        const half8 ax0 = cvt8(xf0, xf1);
        const half8 ax1 = cvt8(xf2, xf3);
        xf0 = *(const float4*)(xbase + CH * Ii);
        xf1 = *(const float4*)(xbase + CH * Ii + 4);
        xf2 = *(const float4*)(xbase + CH * Ii + 32);
        xf3 = *(const float4*)(xbase + CH * Ii + 36);
        const half8 fA0 = wihf[0][t], fA1 = wihf[1][t];
        const half8 fB0 = wihf[2][t], fB1 = wihf[3][t];
        const half8 fC0 = wihf[4][t], fC1 = wihf[5][t];
        const half8 fD0 = wihf[6][t], fD1 = wihf[7][t];
        xw0 = MFMA16(ax0, fA0, splat4(bs[0]));
        xw1 = MFMA16(ax0, fB0, splat4(bs[1]));
        xw2 = MFMA16(ax0, fC0, splat4(bs[2]));
        xw3 = MFMA16(ax0, fD0, splat4(bs[3]));
        xw0 = MFMA16(ax1, fA1, xw0);
        xw1 = MFMA16(ax1, fB1, xw1);
        xw2 = MFMA16(ax1, fC1, xw2);
        xw3 = MFMA16(ax1, fD1, xw3);
    }

    half8 nax0, nax1, wA, wB;          // spread transients
    floatx4 nxw0, nxw1, nxw2, nxw3;    // next chunk's xW+bias accumulators

    float c = 0.0f;                     // stored pre-scaled: c' = -2log2e * c
    __syncthreads();   // h0 + wihf visible (one full drain, outside the loop)

#pragma unroll 1
    for (int n = 0; n < NCH; ++n) {
        const float* xb2 = xbase + (size_t)((n + 2 < NCH) ? n + 2 : NCH - 1) * CH * Ii;

        // step s = 16n + 4P + R; h buffer parity = R&1 (16n+4P even).
        // Chained 2-deep i8 MFMAs (f,g,i first, o trailing); merged-rcp acts;
        // c pre-scaled so e_c = exp2(c) directly.
#define STEP(P, R, CUR, XTRA)                                                 \
        {                                                                     \
            const signed char* hbase = &hbq[CUR][16 * kg];                    \
            const intx4 ah0 = *(const intx4*)(hbase);                         \
            const intx4 ah1 = *(const intx4*)(hbase + 64);                    \
            XTRA;                                                             \
            const intx4 z4 = {0, 0, 0, 0};                                    \
            intx4 qf = MFMAI8(ah0, bqh[1][0], z4);   /* f */                  \
            intx4 qg = MFMAI8(ah0, bqh[2][0], z4);   /* g */                  \
            intx4 qi = MFMAI8(ah0, bqh[0][0], z4);   /* i */                  \
            qf = MFMAI8(ah1, bqh[1][1], qf);                                  \
            qg = MFMAI8(ah1, bqh[2][1], qg);                                  \
            qi = MFMAI8(ah1, bqh[0][1], qi);                                  \
            intx4 qo = MFMAI8(ah0, bqh[3][0], z4);   /* o */                  \
            const float e_f = exp2_(fmaf((float)qf[R], dqh[1], xw1[R]));      \
            const float e_g = exp2_(fmaf((float)qg[R], dqh[2], xw2[R]));      \
            qo = MFMAI8(ah1, bqh[3][1], qo);                                  \
            const float e_i = exp2_(fmaf((float)qi[R], dqh[0], xw0[R]));      \
            const float fg  = fast_rcp(1.0f + e_f);                           \
            const float gv  = fmaf(e_g, 2.8853900817779268f,                  \
                                   -2.8853900817779268f) *                    \
                              fast_rcp((1.0f + e_i) * (1.0f + e_g));          \
            const float e_o = exp2_(fmaf((float)qo[R], dqh[3], xw3[R]));      \
            c = fmaf(fg, c, gv);                                              \
            const float e_c = exp2_(c);                                       \
            const float h   = (1.0f - e_c) *                                  \
                              fast_rcp((1.0f + e_o) * (1.0f + e_c));          \
            if (kg == (P)) {                                                  \
                hbq[(CUR) ^ 1][16 * w + col] =                                \
                    (signed char)(int)rintf(h * 127.f);                       \
                *opr = h;                                                     \
            }                                                                 \
            opr += Hh;                                                        \
            asm volatile("s_waitcnt lgkmcnt(0)\n\ts_barrier" ::: "memory");   \
        }

        // phase P handles steps 4P..4P+3; c lineage hops lane-groups:
        // rotate c from group P-1 (or prev chunk's group 3) into group P.
        // Spread: next-chunk cvt/wihf-reads/f16-MFMAs, then x-prefetch split
        // one load per slot -> 14/16 post-barrier ds_read shadows covered.
#define PHASE(P, X0, X1, X2, X3)                                              \
        STEP(P, 0, 0, X0) STEP(P, 1, 1, X1) STEP(P, 2, 0, X2) STEP(P, 3, 1, X3)

        PHASE(0,
              (c = __shfl(c, (l + 48) & 63), nax0 = cvt8(xf0, xf1)),
              nax1 = cvt8(xf2, xf3),
              (wA = wihf[0][t], wB = wihf[1][t]),
              (nxw0 = MFMA16(nax0, wA, splat4(bs[0])),
               nxw0 = MFMA16(nax1, wB, nxw0)))
        PHASE(1,
              (c = __shfl(c, (l + 48) & 63), wA = wihf[2][t], wB = wihf[3][t]),
              (nxw1 = MFMA16(nax0, wA, splat4(bs[1])),
               nxw1 = MFMA16(nax1, wB, nxw1)),
              (wA = wihf[4][t], wB = wihf[5][t]),
              (nxw2 = MFMA16(nax0, wA, splat4(bs[2])),
               nxw2 = MFMA16(nax1, wB, nxw2)))
        PHASE(2,
              (c = __shfl(c, (l + 48) & 63), wA = wihf[6][t], wB = wihf[7][t]),
              (nxw3 = MFMA16(nax0, wA, splat4(bs[3])),
               nxw3 = MFMA16(nax1, wB, nxw3)),
              xf0 = *(const float4*)(xb2),
              xf1 = *(const float4*)(xb2 + 4))
        PHASE(3,
              (c = __shfl(c, (l + 48) & 63), xf2 = *(const float4*)(xb2 + 32)),
              xf3 = *(const float4*)(xb2 + 36),
              (void)0,
              (void)0)
#undef PHASE
#undef STEP

        xw0 = nxw0; xw1 = nxw1; xw2 = nxw2; xw3 = nxw3;
    }
}

extern "C" void kernel_launch(void* const* d_in, const int* in_sizes, int n_in,
                              void* d_out, int out_size, void* d_ws, size_t ws_size,
                              hipStream_t stream) {
    const float* data = (const float*)d_in[0];
    const float* W_ih = (const float*)d_in[1];
    const float* W_hh = (const float*)d_in[2];
    const float* b_ih = (const float*)d_in[3];
    const float* b_hh = (const float*)d_in[4];
    float* out = (float*)d_out;

    hipLaunchKernelGGL(lstm_i8r4, dim3(256), dim3(512), 0, stream,
                       data, W_ih, W_hh, b_ih, b_hh, out);
}

// Round 14
// 357.688 us; speedup vs baseline: 1.3298x; 1.0132x over previous
//
#include <hip/hip_runtime.h>

// LSTM B=256, T=1024, I=64, H=128. One block/batch row (256 blocks = 256 CUs).
// R22 = R21 (362.4us) + two serial-path cuts (final op-diet round):
//  1. Magic-round i8 quant: fmaf(h,127,2^23+2^22) -> low byte of float bits
//     is the RNE signed i8 (exact for |h*127|<2^22; bit-identical to rintf).
//     Replaces mul+rndne+cvt (3 serial VALU) with 1 fmaf on the path to the
//     h ds_write.
//  2. Unmasked LDS h-write to per-kg slot hbq2[parity][kg][128]: every kg
//     group writes its candidate h (only the true owner's row is read; the
//     read-row index PR is compile-time per STEP). Exec-mask branch moves
//     off the lgkm/barrier path; only the global out store stays masked.
//  - Structural notes (explored, rejected): 2 indep blocks/CU needs B=512;
//    2 rows/block halves CU coverage; row-split needs split barriers (none
//    on CDNA). Exchange-per-step + 8-wave lockstep is structural; if this
//    round lands <1.5% the ~850cyc/step floor is declared.
//  - i8 numerics unchanged: h @ fixed scale 127, W_hh per-row max-abs,
//    lane-local dequant, exp2 consts folded, merged-rcp acts, pre-scaled c.

typedef _Float16 half8  __attribute__((ext_vector_type(8)));
typedef _Float16 half2t __attribute__((ext_vector_type(2)));
typedef float  floatx4  __attribute__((ext_vector_type(4)));
typedef int    intx4   __attribute__((ext_vector_type(4)));

constexpr int Tt = 1024;
constexpr int Ii = 64;
constexpr int Hh = 128;
constexpr int CH = 16;          // timesteps per x chunk-GEMM
constexpr int NCH = Tt / CH;    // 64 chunks

__device__ __forceinline__ float fast_rcp(float x) { return __builtin_amdgcn_rcpf(x); }
__device__ __forceinline__ float exp2_(float x)    { return __builtin_amdgcn_exp2f(x); }
__device__ __forceinline__ half2t pk16(float a, float b) {
    return __builtin_bit_cast(half2t, __builtin_amdgcn_cvt_pkrtz(a, b));
}
#define MFMA16(A, B, C) __builtin_amdgcn_mfma_f32_16x16x32_f16((A), (B), (C), 0, 0, 0)
#define MFMAI8(A, B, C) __builtin_amdgcn_mfma_i32_16x16x64_i8((A), (B), (C), 0, 0, 0)
union H8U { half8 v; half2t p[4]; };

__device__ __forceinline__ half8 cvt8(float4 a, float4 b) {
    H8U u;
    u.p[0] = pk16(a.x, a.y); u.p[1] = pk16(a.z, a.w);
    u.p[2] = pk16(b.x, b.y); u.p[3] = pk16(b.z, b.w);
    return u.v;
}
__device__ __forceinline__ floatx4 splat4(float a) { floatx4 r = {a, a, a, a}; return r; }

// register-only i8x4 pack: low byte = s[0] (little-endian, matches LDS bytes)
__device__ __forceinline__ int pkq4(const float* s, float qs) {
    const int a = (int)rintf(s[0] * qs) & 255;
    const int b = (int)rintf(s[1] * qs) & 255;
    const int c = (int)rintf(s[2] * qs) & 255;
    const int d = (int)rintf(s[3] * qs) & 255;
    return a | (b << 8) | (c << 16) | (d << 24);
}

__global__ __launch_bounds__(512, 1) void lstm_i8r5(
    const float* __restrict__ data,   // [B, T, I]
    const float* __restrict__ W_ih,   // [4H, I]
    const float* __restrict__ W_hh,   // [4H, H]
    const float* __restrict__ b_ih,   // [4H]
    const float* __restrict__ b_hh,   // [4H]
    float* __restrict__ out)          // [B, T, H] f32
{
    const int b   = blockIdx.x;
    const int t   = threadIdx.x;
    const int w   = t >> 6;    // wave 0..7
    const int l   = t & 63;    // lane
    const int col = l & 15;    // N-col == hidden unit offset within wave's 16
    const int kg  = l >> 4;    // k-group / C-row group

    // LDS: Wih fragments (64KB) + per-kg h candidate slots (1KB)
    __shared__ __align__(16) half8 wihf[8][512];          // [g*2+s][thread]
    __shared__ __align__(16) signed char hbq2[2][4][Hh];  // [parity][kg][h]
    if (t < Hh) hbq2[0][3][t] = 0;    // h0 = 0 (first step reads [0][3])

    // gates 0(i),1(f),3(o): sigma(x)=rcp(1+exp2(-log2e*x))
    // gate 2(g):            tanh(x) via e=exp2(-2log2e*x), (1-e)*rcp(1+e)
    intx4 bqh[4][2];   // Whh int8: 4 gates x 2 K-slices (K=128 as 2x64)
    float dqh[4];      // per-gate-row dequant scale (sc folded)
    float bs[4];       // scaled bias (x chunk-GEMM C-init)
#pragma unroll
    for (int g = 0; g < 4; ++g) {
        const float sc = (g == 2) ? -2.8853900817779268f : -1.4426950408889634f;
        const int row = 128 * g + 16 * w + col;
        bs[g] = sc * (b_ih[row] + b_hh[row]);
        const float* wh = W_hh + (size_t)row * Hh;
        const float* wi = W_ih + (size_t)row * Ii;
        // Whh: row max-abs then i8 quantize (register-only pack)
        float mw = 1e-20f;
#pragma unroll
        for (int k = 0; k < Hh; k += 4) {
            const float4 f = *(const float4*)(wh + k);
            mw = fmaxf(mw, fmaxf(fmaxf(fabsf(f.x), fabsf(f.y)),
                                 fmaxf(fabsf(f.z), fabsf(f.w))));
        }
        const float qs = 127.f / mw;
        dqh[g] = sc * mw * (1.f / (127.f * 127.f));
#pragma unroll
        for (int s = 0; s < 2; ++s) {
            const float* src = wh + 64 * s + 16 * kg;
            intx4 q;
            q[0] = pkq4(src + 0,  qs);
            q[1] = pkq4(src + 4,  qs);
            q[2] = pkq4(src + 8,  qs);
            q[3] = pkq4(src + 12, qs);
            bqh[g][s] = q;
        }
        // Wih fragments (sc folded) -> LDS, per-lane identity slot
#pragma unroll
        for (int s = 0; s < 2; ++s) {
            const float* src = wi + 32 * s + 8 * kg;
            const float4 f0 = ((const float4*)src)[0];
            const float4 f1 = ((const float4*)src)[1];
            H8U u;
            u.p[0] = pk16(sc * f0.x, sc * f0.y); u.p[1] = pk16(sc * f0.z, sc * f0.w);
            u.p[2] = pk16(sc * f1.x, sc * f1.y); u.p[3] = pk16(sc * f1.z, sc * f1.w);
            wihf[g * 2 + s][t] = u.v;
        }
    }

    const float* xp  = data + (size_t)b * Tt * Ii;
    float*       opr = out  + (size_t)b * Tt * Hh + 16 * w + col;

    // x chunk staging: lane reads x[t0 + (l&15)][32*s2 + 8*kg + j], j=0..7
    const float* xbase = xp + (size_t)(l & 15) * Ii + 8 * kg;
    float4 xf0 = *(const float4*)(xbase);
    float4 xf1 = *(const float4*)(xbase + 4);
    float4 xf2 = *(const float4*)(xbase + 32);
    float4 xf3 = *(const float4*)(xbase + 36);

    // ---- prologue: chunk-0 xw lump, chunk-1 x loads in flight under it ----
    floatx4 xw0, xw1, xw2, xw3;
    {
        const half8 ax0 = cvt8(xf0, xf1);
        const half8 ax1 = cvt8(xf2, xf3);
        xf0 = *(const float4*)(xbase + CH * Ii);
        xf1 = *(const float4*)(xbase + CH * Ii + 4);
        xf2 = *(const float4*)(xbase + CH * Ii + 32);
        xf3 = *(const float4*)(xbase + CH * Ii + 36);
        const half8 fA0 = wihf[0][t], fA1 = wihf[1][t];
        const half8 fB0 = wihf[2][t], fB1 = wihf[3][t];
        const half8 fC0 = wihf[4][t], fC1 = wihf[5][t];
        const half8 fD0 = wihf[6][t], fD1 = wihf[7][t];
        xw0 = MFMA16(ax0, fA0, splat4(bs[0]));
        xw1 = MFMA16(ax0, fB0, splat4(bs[1]));
        xw2 = MFMA16(ax0, fC0, splat4(bs[2]));
        xw3 = MFMA16(ax0, fD0, splat4(bs[3]));
        xw0 = MFMA16(ax1, fA1, xw0);
        xw1 = MFMA16(ax1, fB1, xw1);
        xw2 = MFMA16(ax1, fC1, xw2);
        xw3 = MFMA16(ax1, fD1, xw3);
    }

    half8 nax0, nax1, wA, wB;          // spread transients
    floatx4 nxw0, nxw1, nxw2, nxw3;    // next chunk's xW+bias accumulators

    float c = 0.0f;                     // stored pre-scaled: c' = -2log2e * c
    __syncthreads();   // h0 + wihf visible (one full drain, outside the loop)

#pragma unroll 1
    for (int n = 0; n < NCH; ++n) {
        const float* xb2 = xbase + (size_t)((n + 2 < NCH) ? n + 2 : NCH - 1) * CH * Ii;

        // step s = 16n + 4P + R; h buffer parity = R&1 (16n+4P even).
        // PR = kg-row written by the previous step's owner (compile-time).
        // Chained 2-deep i8 MFMAs (f,g,i first, o trailing); merged-rcp acts;
        // c pre-scaled so e_c = exp2(c); magic-round i8 quant; unmasked
        // per-kg LDS h-write (only global store masked).
#define STEP(P, PR, R, CUR, XTRA)                                             \
        {                                                                     \
            const signed char* hbase = &hbq2[CUR][PR][16 * kg];               \
            const intx4 ah0 = *(const intx4*)(hbase);                         \
            const intx4 ah1 = *(const intx4*)(hbase + 64);                    \
            XTRA;                                                             \
            const intx4 z4 = {0, 0, 0, 0};                                    \
            intx4 qf = MFMAI8(ah0, bqh[1][0], z4);   /* f */                  \
            intx4 qg = MFMAI8(ah0, bqh[2][0], z4);   /* g */                  \
            intx4 qi = MFMAI8(ah0, bqh[0][0], z4);   /* i */                  \
            qf = MFMAI8(ah1, bqh[1][1], qf);                                  \
            qg = MFMAI8(ah1, bqh[2][1], qg);                                  \
            qi = MFMAI8(ah1, bqh[0][1], qi);                                  \
            intx4 qo = MFMAI8(ah0, bqh[3][0], z4);   /* o */                  \
            const float e_f = exp2_(fmaf((float)qf[R], dqh[1], xw1[R]));      \
            const float e_g = exp2_(fmaf((float)qg[R], dqh[2], xw2[R]));      \
            qo = MFMAI8(ah1, bqh[3][1], qo);                                  \
            const float e_i = exp2_(fmaf((float)qi[R], dqh[0], xw0[R]));      \
            const float fg  = fast_rcp(1.0f + e_f);                           \
            const float gv  = fmaf(e_g, 2.8853900817779268f,                  \
                                   -2.8853900817779268f) *                    \
                              fast_rcp((1.0f + e_i) * (1.0f + e_g));          \
            const float e_o = exp2_(fmaf((float)qo[R], dqh[3], xw3[R]));      \
            c = fmaf(fg, c, gv);                                              \
            const float e_c = exp2_(c);                                       \
            const float h   = (1.0f - e_c) *                                  \
                              fast_rcp((1.0f + e_o) * (1.0f + e_c));          \
            const float hq  = fmaf(h, 127.0f, 12582912.0f);                   \
            hbq2[(CUR) ^ 1][kg][16 * w + col] =                               \
                (signed char)(__builtin_bit_cast(unsigned, hq) & 0xFFu);      \
            if (kg == (P)) *opr = h;                                          \
            opr += Hh;                                                        \
            asm volatile("s_waitcnt lgkmcnt(0)\n\ts_barrier" ::: "memory");   \
        }

        // phase P handles steps 4P..4P+3; c lineage hops lane-groups:
        // rotate c from group P-1 (or prev chunk's group 3) into group P.
        // Spread: next-chunk cvt/wihf-reads/f16-MFMAs/x-prefetch fill XTRA.
#define PHASE(P, PRM1, X0, X1, X2, X3)                                        \
        STEP(P, PRM1, 0, 0, X0) STEP(P, P, 1, 1, X1)                          \
        STEP(P, P, 2, 0, X2)    STEP(P, P, 3, 1, X3)

        PHASE(0, 3,
              (c = __shfl(c, (l + 48) & 63), nax0 = cvt8(xf0, xf1)),
              nax1 = cvt8(xf2, xf3),
              (wA = wihf[0][t], wB = wihf[1][t]),
              (nxw0 = MFMA16(nax0, wA, splat4(bs[0])),
               nxw0 = MFMA16(nax1, wB, nxw0)))
        PHASE(1, 0,
              (c = __shfl(c, (l + 48) & 63), wA = wihf[2][t], wB = wihf[3][t]),
              (nxw1 = MFMA16(nax0, wA, splat4(bs[1])),
               nxw1 = MFMA16(nax1, wB, nxw1)),
              (wA = wihf[4][t], wB = wihf[5][t]),
              (nxw2 = MFMA16(nax0, wA, splat4(bs[2])),
               nxw2 = MFMA16(nax1, wB, nxw2)))
        PHASE(2, 1,
              (c = __shfl(c, (l + 48) & 63), wA = wihf[6][t], wB = wihf[7][t]),
              (nxw3 = MFMA16(nax0, wA, splat4(bs[3])),
               nxw3 = MFMA16(nax1, wB, nxw3)),
              xf0 = *(const float4*)(xb2),
              xf1 = *(const float4*)(xb2 + 4))
        PHASE(3, 2,
              (c = __shfl(c, (l + 48) & 63), xf2 = *(const float4*)(xb2 + 32)),
              xf3 = *(const float4*)(xb2 + 36),
              (void)0,
              (void)0)
#undef PHASE
#undef STEP

        xw0 = nxw0; xw1 = nxw1; xw2 = nxw2; xw3 = nxw3;
    }
}

extern "C" void kernel_launch(void* const* d_in, const int* in_sizes, int n_in,
                              void* d_out, int out_size, void* d_ws, size_t ws_size,
                              hipStream_t stream) {
    const float* data = (const float*)d_in[0];
    const float* W_ih = (const float*)d_in[1];
    const float* W_hh = (const float*)d_in[2];
    const float* b_ih = (const float*)d_in[3];
    const float* b_hh = (const float*)d_in[4];
    float* out = (float*)d_out;

    hipLaunchKernelGGL(lstm_i8r5, dim3(256), dim3(512), 0, stream,
                       data, W_ih, W_hh, b_ih, b_hh, out);
}

// Round 15
// 357.282 us; speedup vs baseline: 1.3313x; 1.0011x over previous
//
#include <hip/hip_runtime.h>

// LSTM B=256, T=1024, I=64, H=128. One block/batch row (256 blocks = 256 CUs).
// R23 = R22 (357.7us) + bank-conflict fix on the per-kg h-write:
//  - R22's unmasked write put kg rows at stride 128B (= 32 banks x 4B), so
//    the 4 kg groups of a wave hit the SAME 4 banks -> 4-way write conflict,
//    SQ_LDS_BANK_CONFLICT 0 -> 4.19M/dispatch (~16 cyc/step).
//  - Fix: row stride 160B (40 dwords). kg row k starts at dword 40k; its 4
//    write dwords occupy banks (8k+4w..+3) mod 32 -- disjoint across the 4
//    kg groups of each wave. Reads remain broadcast (conflict-free).
//  - Everything else identical to R22: magic-round i8 quant
//    (fmaf(h,127,2^23+2^22), RNE-exact), unmasked per-kg h-write, chained
//    2-deep i8 MFMA, merged-rcp acts, pre-scaled c, spread chunk-GEMM.
//  - PRE-COMMIT: <1.5% gain here => ~830cyc/step floor is structural
//    (serial chain ~300 + sync/skew + lockstep contention; M-batching
//    blocked by B=256=CU count) -> declare ceiling next round.

typedef _Float16 half8  __attribute__((ext_vector_type(8)));
typedef _Float16 half2t __attribute__((ext_vector_type(2)));
typedef float  floatx4  __attribute__((ext_vector_type(4)));
typedef int    intx4   __attribute__((ext_vector_type(4)));

constexpr int Tt = 1024;
constexpr int Ii = 64;
constexpr int Hh = 128;
constexpr int CH = 16;          // timesteps per x chunk-GEMM
constexpr int NCH = Tt / CH;    // 64 chunks
constexpr int HS = 160;         // h-row stride (bytes): bank-disjoint kg rows

__device__ __forceinline__ float fast_rcp(float x) { return __builtin_amdgcn_rcpf(x); }
__device__ __forceinline__ float exp2_(float x)    { return __builtin_amdgcn_exp2f(x); }
__device__ __forceinline__ half2t pk16(float a, float b) {
    return __builtin_bit_cast(half2t, __builtin_amdgcn_cvt_pkrtz(a, b));
}
#define MFMA16(A, B, C) __builtin_amdgcn_mfma_f32_16x16x32_f16((A), (B), (C), 0, 0, 0)
#define MFMAI8(A, B, C) __builtin_amdgcn_mfma_i32_16x16x64_i8((A), (B), (C), 0, 0, 0)
union H8U { half8 v; half2t p[4]; };

__device__ __forceinline__ half8 cvt8(float4 a, float4 b) {
    H8U u;
    u.p[0] = pk16(a.x, a.y); u.p[1] = pk16(a.z, a.w);
    u.p[2] = pk16(b.x, b.y); u.p[3] = pk16(b.z, b.w);
    return u.v;
}
__device__ __forceinline__ floatx4 splat4(float a) { floatx4 r = {a, a, a, a}; return r; }

// register-only i8x4 pack: low byte = s[0] (little-endian, matches LDS bytes)
__device__ __forceinline__ int pkq4(const float* s, float qs) {
    const int a = (int)rintf(s[0] * qs) & 255;
    const int b = (int)rintf(s[1] * qs) & 255;
    const int c = (int)rintf(s[2] * qs) & 255;
    const int d = (int)rintf(s[3] * qs) & 255;
    return a | (b << 8) | (c << 16) | (d << 24);
}

__global__ __launch_bounds__(512, 1) void lstm_i8r6(
    const float* __restrict__ data,   // [B, T, I]
    const float* __restrict__ W_ih,   // [4H, I]
    const float* __restrict__ W_hh,   // [4H, H]
    const float* __restrict__ b_ih,   // [4H]
    const float* __restrict__ b_hh,   // [4H]
    float* __restrict__ out)          // [B, T, H] f32
{
    const int b   = blockIdx.x;
    const int t   = threadIdx.x;
    const int w   = t >> 6;    // wave 0..7
    const int l   = t & 63;    // lane
    const int col = l & 15;    // N-col == hidden unit offset within wave's 16
    const int kg  = l >> 4;    // k-group / C-row group

    // LDS: Wih fragments (64KB) + per-kg h candidate rows (2x4x160B)
    __shared__ __align__(16) half8 wihf[8][512];           // [g*2+s][thread]
    __shared__ __align__(16) signed char hbq2[2][4][HS];   // [parity][kg][h]
    if (t < Hh) hbq2[0][3][t] = 0;    // h0 = 0 (first step reads [0][3])

    // gates 0(i),1(f),3(o): sigma(x)=rcp(1+exp2(-log2e*x))
    // gate 2(g):            tanh(x) via e=exp2(-2log2e*x), (1-e)*rcp(1+e)
    intx4 bqh[4][2];   // Whh int8: 4 gates x 2 K-slices (K=128 as 2x64)
    float dqh[4];      // per-gate-row dequant scale (sc folded)
    float bs[4];       // scaled bias (x chunk-GEMM C-init)
#pragma unroll
    for (int g = 0; g < 4; ++g) {
        const float sc = (g == 2) ? -2.8853900817779268f : -1.4426950408889634f;
        const int row = 128 * g + 16 * w + col;
        bs[g] = sc * (b_ih[row] + b_hh[row]);
        const float* wh = W_hh + (size_t)row * Hh;
        const float* wi = W_ih + (size_t)row * Ii;
        // Whh: row max-abs then i8 quantize (register-only pack)
        float mw = 1e-20f;
#pragma unroll
        for (int k = 0; k < Hh; k += 4) {
            const float4 f = *(const float4*)(wh + k);
            mw = fmaxf(mw, fmaxf(fmaxf(fabsf(f.x), fabsf(f.y)),
                                 fmaxf(fabsf(f.z), fabsf(f.w))));
        }
        const float qs = 127.f / mw;
        dqh[g] = sc * mw * (1.f / (127.f * 127.f));
#pragma unroll
        for (int s = 0; s < 2; ++s) {
            const float* src = wh + 64 * s + 16 * kg;
            intx4 q;
            q[0] = pkq4(src + 0,  qs);
            q[1] = pkq4(src + 4,  qs);
            q[2] = pkq4(src + 8,  qs);
            q[3] = pkq4(src + 12, qs);
            bqh[g][s] = q;
        }
        // Wih fragments (sc folded) -> LDS, per-lane identity slot
#pragma unroll
        for (int s = 0; s < 2; ++s) {
            const float* src = wi + 32 * s + 8 * kg;
            const float4 f0 = ((const float4*)src)[0];
            const float4 f1 = ((const float4*)src)[1];
            H8U u;
            u.p[0] = pk16(sc * f0.x, sc * f0.y); u.p[1] = pk16(sc * f0.z, sc * f0.w);
            u.p[2] = pk16(sc * f1.x, sc * f1.y); u.p[3] = pk16(sc * f1.z, sc * f1.w);
            wihf[g * 2 + s][t] = u.v;
        }
    }

    const float* xp  = data + (size_t)b * Tt * Ii;
    float*       opr = out  + (size_t)b * Tt * Hh + 16 * w + col;

    // x chunk staging: lane reads x[t0 + (l&15)][32*s2 + 8*kg + j], j=0..7
    const float* xbase = xp + (size_t)(l & 15) * Ii + 8 * kg;
    float4 xf0 = *(const float4*)(xbase);
    float4 xf1 = *(const float4*)(xbase + 4);
    float4 xf2 = *(const float4*)(xbase + 32);
    float4 xf3 = *(const float4*)(xbase + 36);

    // ---- prologue: chunk-0 xw lump, chunk-1 x loads in flight under it ----
    floatx4 xw0, xw1, xw2, xw3;
    {
        const half8 ax0 = cvt8(xf0, xf1);
        const half8 ax1 = cvt8(xf2, xf3);
        xf0 = *(const float4*)(xbase + CH * Ii);
        xf1 = *(const float4*)(xbase + CH * Ii + 4);
        xf2 = *(const float4*)(xbase + CH * Ii + 32);
        xf3 = *(const float4*)(xbase + CH * Ii + 36);
        const half8 fA0 = wihf[0][t], fA1 = wihf[1][t];
        const half8 fB0 = wihf[2][t], fB1 = wihf[3][t];
        const half8 fC0 = wihf[4][t], fC1 = wihf[5][t];
        const half8 fD0 = wihf[6][t], fD1 = wihf[7][t];
        xw0 = MFMA16(ax0, fA0, splat4(bs[0]));
        xw1 = MFMA16(ax0, fB0, splat4(bs[1]));
        xw2 = MFMA16(ax0, fC0, splat4(bs[2]));
        xw3 = MFMA16(ax0, fD0, splat4(bs[3]));
        xw0 = MFMA16(ax1, fA1, xw0);
        xw1 = MFMA16(ax1, fB1, xw1);
        xw2 = MFMA16(ax1, fC1, xw2);
        xw3 = MFMA16(ax1, fD1, xw3);
    }

    half8 nax0, nax1, wA, wB;          // spread transients
    floatx4 nxw0, nxw1, nxw2, nxw3;    // next chunk's xW+bias accumulators

    float c = 0.0f;                     // stored pre-scaled: c' = -2log2e * c
    __syncthreads();   // h0 + wihf visible (one full drain, outside the loop)

#pragma unroll 1
    for (int n = 0; n < NCH; ++n) {
        const float* xb2 = xbase + (size_t)((n + 2 < NCH) ? n + 2 : NCH - 1) * CH * Ii;

        // step s = 16n + 4P + R; h buffer parity = R&1 (16n+4P even).
        // PR = kg-row written by the previous step's owner (compile-time).
#define STEP(P, PR, R, CUR, XTRA)                                             \
        {                                                                     \
            const signed char* hbase = &hbq2[CUR][PR][16 * kg];               \
            const intx4 ah0 = *(const intx4*)(hbase);                         \
            const intx4 ah1 = *(const intx4*)(hbase + 64);                    \
            XTRA;                                                             \
            const intx4 z4 = {0, 0, 0, 0};                                    \
            intx4 qf = MFMAI8(ah0, bqh[1][0], z4);   /* f */                  \
            intx4 qg = MFMAI8(ah0, bqh[2][0], z4);   /* g */                  \
            intx4 qi = MFMAI8(ah0, bqh[0][0], z4);   /* i */                  \
            qf = MFMAI8(ah1, bqh[1][1], qf);                                  \
            qg = MFMAI8(ah1, bqh[2][1], qg);                                  \
            qi = MFMAI8(ah1, bqh[0][1], qi);                                  \
            intx4 qo = MFMAI8(ah0, bqh[3][0], z4);   /* o */                  \
            const float e_f = exp2_(fmaf((float)qf[R], dqh[1], xw1[R]));      \
            const float e_g = exp2_(fmaf((float)qg[R], dqh[2], xw2[R]));      \
            qo = MFMAI8(ah1, bqh[3][1], qo);                                  \
            const float e_i = exp2_(fmaf((float)qi[R], dqh[0], xw0[R]));      \
            const float fg  = fast_rcp(1.0f + e_f);                           \
            const float gv  = fmaf(e_g, 2.8853900817779268f,                  \
                                   -2.8853900817779268f) *                    \
                              fast_rcp((1.0f + e_i) * (1.0f + e_g));          \
            const float e_o = exp2_(fmaf((float)qo[R], dqh[3], xw3[R]));      \
            c = fmaf(fg, c, gv);                                              \
            const float e_c = exp2_(c);                                       \
            const float h   = (1.0f - e_c) *                                  \
                              fast_rcp((1.0f + e_o) * (1.0f + e_c));          \
            const float hq  = fmaf(h, 127.0f, 12582912.0f);                   \
            hbq2[(CUR) ^ 1][kg][16 * w + col] =                               \
                (signed char)(__builtin_bit_cast(unsigned, hq) & 0xFFu);      \
            if (kg == (P)) *opr = h;                                          \
            opr += Hh;                                                        \
            asm volatile("s_waitcnt lgkmcnt(0)\n\ts_barrier" ::: "memory");   \
        }

        // phase P handles steps 4P..4P+3; c lineage hops lane-groups:
        // rotate c from group P-1 (or prev chunk's group 3) into group P.
        // Spread: next-chunk cvt/wihf-reads/f16-MFMAs/x-prefetch fill XTRA.
#define PHASE(P, PRM1, X0, X1, X2, X3)                                        \
        STEP(P, PRM1, 0, 0, X0) STEP(P, P, 1, 1, X1)                          \
        STEP(P, P, 2, 0, X2)    STEP(P, P, 3, 1, X3)

        PHASE(0, 3,
              (c = __shfl(c, (l + 48) & 63), nax0 = cvt8(xf0, xf1)),
              nax1 = cvt8(xf2, xf3),
              (wA = wihf[0][t], wB = wihf[1][t]),
              (nxw0 = MFMA16(nax0, wA, splat4(bs[0])),
               nxw0 = MFMA16(nax1, wB, nxw0)))
        PHASE(1, 0,
              (c = __shfl(c, (l + 48) & 63), wA = wihf[2][t], wB = wihf[3][t]),
              (nxw1 = MFMA16(nax0, wA, splat4(bs[1])),
               nxw1 = MFMA16(nax1, wB, nxw1)),
              (wA = wihf[4][t], wB = wihf[5][t]),
              (nxw2 = MFMA16(nax0, wA, splat4(bs[2])),
               nxw2 = MFMA16(nax1, wB, nxw2)))
        PHASE(2, 1,
              (c = __shfl(c, (l + 48) & 63), wA = wihf[6][t], wB = wihf[7][t]),
              (nxw3 = MFMA16(nax0, wA, splat4(bs[3])),
               nxw3 = MFMA16(nax1, wB, nxw3)),
              xf0 = *(const float4*)(xb2),
              xf1 = *(const float4*)(xb2 + 4))
        PHASE(3, 2,
              (c = __shfl(c, (l + 48) & 63), xf2 = *(const float4*)(xb2 + 32)),
              xf3 = *(const float4*)(xb2 + 36),
              (void)0,
              (void)0)
#undef PHASE
#undef STEP

        xw0 = nxw0; xw1 = nxw1; xw2 = nxw2; xw3 = nxw3;
    }
}

extern "C" void kernel_launch(void* const* d_in, const int* in_sizes, int n_in,
                              void* d_out, int out_size, void* d_ws, size_t ws_size,
                              hipStream_t stream) {
    const float* data = (const float*)d_in[0];
    const float* W_ih = (const float*)d_in[1];
    const float* W_hh = (const float*)d_in[2];
    const float* b_ih = (const float*)d_in[3];
    const float* b_hh = (const float*)d_in[4];
    float* out = (float*)d_out;

    hipLaunchKernelGGL(lstm_i8r6, dim3(256), dim3(512), 0, stream,
                       data, W_ih, W_hh, b_ih, b_hh, out);
}